// Round 5
// baseline (454.547 us; speedup 1.0000x reference)
//
#include <hip/hip_runtime.h>
#include <hip/hip_bf16.h>

typedef __bf16 bf16x8 __attribute__((ext_vector_type(8)));
typedef __bf16 bf16x4 __attribute__((ext_vector_type(4)));
typedef float f32x4 __attribute__((ext_vector_type(4)));

#define ROWSG 32768          // B*T
#define RB 6                 // bt rows per block -> 54 valid + 10 pad = 64 supertile rows
#define NBLK 5462            // ceil(32768/6)
#define HPAD 72              // bf16 row stride
#define NN_OFF ((size_t)ROWSG)
#define EYE_OFF ((size_t)ROWSG + (size_t)ROWSG*64)

// weight-cache offsets (bf16 elements), all WT[n][k] row-major, stride = Kp
#define OFF_EW1   0          // 64 x 224 (K=200 zero-padded)
#define OFF_EW2   14336      // 64 x 64
#define OFF_WQ    18432
#define OFF_WK    22528
#define OFF_WV    26624
#define OFF_WO    30720
#define OFF_F1    34816
#define OFF_F2    38912
#define OFF_W1A   43008      // 64 x 128
#define OFF_W1B   51200      // 256 x 64
#define OFF_HB1W  67584      // 32 x 128
#define OFF_W2A   71680      // 64 x 128
#define OFF_W2B   79872      // 32 x 64
#define OFF_HB2W1 81920      // 32 x 128
#define OFF_NI    86016      // 8 mats x 16(e-pad) x 64 bf16 = 8192  (fc2ni transposed)
#define WS_TOTAL  94208

__device__ __align__(16) __bf16 g_ws[WS_TOTAL];

#define MFMA16(a,b,c) __builtin_amdgcn_mfma_f32_16x16x32_bf16(a,b,c,0,0,0)

// ---------------- weight transform kernel ----------------
struct TP { const float* src[15]; };

__global__ __launch_bounds__(256) void wtrans(TP tp) {
    const int gid = blockIdx.x * 256 + threadIdx.x;
    if (gid >= WS_TOTAL) return;
    if (gid >= OFF_NI) {
        // fc2ni [n][d][e] (8,64,7) -> [n][e'][d], e' padded to 16 with zeros
        const int loc = gid - OFF_NI;
        const int nmat = loc >> 10, rem = loc & 1023, e = rem >> 6, k = rem & 63;
        float v = (e < 7) ? tp.src[14][nmat * 448 + k * 7 + e] : 0.f;
        g_ws[gid] = (__bf16)v;
        return;
    }
    const int OFFS[14] = {OFF_EW1, OFF_EW2, OFF_WQ, OFF_WK, OFF_WV, OFF_WO, OFF_F1,
                          OFF_F2, OFF_W1A, OFF_W1B, OFF_HB1W, OFF_W2A, OFF_W2B, OFF_HB2W1};
    const int KPS[14]  = {224, 64, 64, 64, 64, 64, 64, 64, 128, 64, 128, 128, 64, 128};
    const int KRS[14]  = {200, 64, 64, 64, 64, 64, 64, 64, 128, 64, 128, 128, 64, 128};
    const int NS[14]   = {64, 64, 64, 64, 64, 64, 64, 64, 64, 256, 32, 64, 32, 32};
    int m = 0;
#pragma unroll
    for (int i = 1; i < 14; ++i) if (gid >= OFFS[i]) m = i;
    const int loc = gid - OFFS[m];
    const int Kp = KPS[m];
    const int n = loc / Kp;
    const int k = loc - n * Kp;
    float v = 0.f;
    if (k < KRS[m]) v = tp.src[m][(size_t)k * NS[m] + n];   // src is W[k][n]
    g_ws[gid] = (__bf16)v;
}

// ---------------- main fused kernel ----------------
struct MainP {
    const float *qvals, *states, *hid, *eb1, *eb2, *bq, *bk, *bv, *bo,
        *l1g, *l1b, *fb1, *fb2, *l2g, *l2b, *niw, *nib, *ng, *nb,
        *b1a, *b1b, *hb1b, *b2a, *b2b, *hb2b1, *hw2, *hb2b2;
    float* out;
};

// projection + bias + residual + LayerNorm over the 64-row supertile; wave w owns M-window w.
// Entirely wave-local: A rows w*16+l15, H rows w*16+quad*4+r.
__device__ __forceinline__ void proj_ln4(const __bf16* A, const __bf16* WT,
                                         const float* bias, const float* g, const float* bb,
                                         __bf16* H, int w, int quad, int l15) {
    const int mt = w;
    f32x4 acc0 = {0,0,0,0}, acc1 = {0,0,0,0}, acc2 = {0,0,0,0}, acc3 = {0,0,0,0};
#pragma unroll
    for (int ks = 0; ks < 2; ++ks) {
        const int kk = ks * 32 + quad * 8;
        const bf16x8 af = *(const bf16x8*)(A + (mt * 16 + l15) * HPAD + kk);
        acc0 = MFMA16(af, *(const bf16x8*)(WT + (size_t)(0 * 16 + l15) * 64 + kk), acc0);
        acc1 = MFMA16(af, *(const bf16x8*)(WT + (size_t)(1 * 16 + l15) * 64 + kk), acc1);
        acc2 = MFMA16(af, *(const bf16x8*)(WT + (size_t)(2 * 16 + l15) * 64 + kk), acc2);
        acc3 = MFMA16(af, *(const bf16x8*)(WT + (size_t)(3 * 16 + l15) * 64 + kk), acc3);
    }
    float v[4][4], g4[4], b4[4];
#pragma unroll
    for (int nt = 0; nt < 4; ++nt) {
        const int col = nt * 16 + l15;
        const float bo = bias[col];
        g4[nt] = g[col]; b4[nt] = bb[col];
        const f32x4 a = (nt == 0) ? acc0 : (nt == 1) ? acc1 : (nt == 2) ? acc2 : acc3;
#pragma unroll
        for (int r = 0; r < 4; ++r)
            v[nt][r] = a[r] + bo + (float)H[(mt * 16 + quad * 4 + r) * HPAD + col];
    }
#pragma unroll
    for (int r = 0; r < 4; ++r) {
        float s  = v[0][r] + v[1][r] + v[2][r] + v[3][r];
        float s2 = v[0][r]*v[0][r] + v[1][r]*v[1][r] + v[2][r]*v[2][r] + v[3][r]*v[3][r];
#pragma unroll
        for (int off = 1; off < 16; off <<= 1) {
            s  += __shfl_xor(s,  off, 64);
            s2 += __shfl_xor(s2, off, 64);
        }
        const float mu  = s * 0.015625f;
        const float var = s2 * 0.015625f - mu * mu;
        const float rs  = rsqrtf(var + 1e-5f);
#pragma unroll
        for (int nt = 0; nt < 4; ++nt)
            H[(mt * 16 + quad * 4 + r) * HPAD + nt * 16 + l15] =
                (__bf16)((v[nt][r] - mu) * rs * g4[nt] + b4[nt]);
    }
}

// RB=6 supertile (64 rows), wave w owns M-window w in all 64-row GEMM phases.
// 9 barriers total; P6a->LN1->FFN1->LN2 is one wave-local barrier-free chain.
__global__ __launch_bounds__(256) void mixer_main(MainP p) {
    __shared__ __align__(16) __bf16 Hb[64 * HPAD];   // h -> h2 -> h3              (9216 B)
    __shared__ __align__(16) __bf16 Qb[64 * HPAD];   // Sb | q/attv | tail scratch (9216 B)
    __shared__ __align__(16) __bf16 Kb[64 * HPAD];   // k -> ah -> ffn hid | ensB  (9216 B)
    __shared__ __align__(16) __bf16 EbU[16 * HPAD];  // e | encS(rows 8..13) | Tb1 (2304 B)
    __shared__ __align__(16) float  attU[6 * 108];   // att probs, 12-float rows   (2592 B)
    // total 32544 B -> 5 blocks/CU

    // aliases into Qb (disjoint lifetimes)
    __bf16* Sb   = Qb;                       // 6x224 bf16 = 2688B      [P0..P1]
    __bf16* W1bS = Qb;                       // 6x256 bf16 = 3072B      [P10s2..P11]
    float*  B1f  = (float*)(Qb + 1536);      // @3072B..3840B
    float*  W2f  = (float*)(Qb + 1920);      // @3840B..4608B
    float*  T3f  = (float*)(Qb + 2304);      // @4608B..5376B
    __bf16* Tb2  = Qb + 2688;                // @5376B..7680B, 16x72    [P10s1..P10s2]
    float*  sNiP = (float*)(Qb + 3840);      // @7680B..9024B, 336 f32  [P9..P9b]
    float*  qniL = (float*)(Qb + 4512);      // @9024B..9216B, 48 f32   [P9b..P11]
    __bf16* ensB = Kb;                       // 6x136 bf16 = 1632B      [P8b..P10s2]

    const int blk = blockIdx.x;
    const int bt0 = blk * RB;
    const int t = threadIdx.x;
    const int w = t >> 6, lane = t & 63, quad = lane >> 4, l15 = lane & 15;
    const __bf16* ws = g_ws;

    // ---- P0: stage hidden_state -> Hb; states -> Sb ----
#pragma unroll
    for (int it = 0; it < 3; ++it) {
        const int u = it * 256 + t;               // 768 float4 units = 6 rows x 512 floats
        const int x = u >> 7, rem = u & 127, n = rem >> 4, d4 = (rem & 15) * 4;
        const int bt = bt0 + x;
        const size_t btc = (bt < ROWSG) ? bt : (ROWSG - 1);
        const float4 v4 = *(const float4*)(p.hid + (btc * 512 + n * 64 + d4));
        bf16x4 o; o[0] = (__bf16)v4.x; o[1] = (__bf16)v4.y; o[2] = (__bf16)v4.z; o[3] = (__bf16)v4.w;
        *(bf16x4*)(Hb + (x * 9 + n) * HPAD + d4) = o;
    }
#pragma unroll
    for (int it = 0; it < 2; ++it) {
        const int u = it * 256 + t;               // 300 float4 units = 6 rows x 200 floats
        if (u < 300) {
            const int xr = u / 50, c4 = u - xr * 50;
            const int bt = bt0 + xr;
            const size_t btc = (bt < ROWSG) ? bt : (ROWSG - 1);
            const float4 v4 = *(const float4*)(p.states + btc * 200 + c4 * 4);
            bf16x4 o; o[0] = (__bf16)v4.x; o[1] = (__bf16)v4.y; o[2] = (__bf16)v4.z; o[3] = (__bf16)v4.w;
            *(bf16x4*)(Sb + xr * 224 + c4 * 4) = o;
        }
    }
    if (t < 144) { const int xr = t / 24, c = t - xr * 24; Sb[xr * 224 + 200 + c] = (__bf16)0.0f; }
    __syncthreads();

    // ---- P1: e = relu(S @ EW1 + eb1); row clamp for garbage A rows ----
    float e4[4];
    {
        const int n0 = w * 16;
        const int srow = (l15 < RB) ? l15 : (RB - 1);
        f32x4 acc = {0, 0, 0, 0};
        for (int ks = 0; ks < 7; ++ks) {
            const int kk = ks * 32 + quad * 8;
            const bf16x8 af = *(const bf16x8*)(Sb + srow * 224 + kk);
            const bf16x8 bf = *(const bf16x8*)(ws + OFF_EW1 + (size_t)(n0 + l15) * 224 + kk);
            acc = MFMA16(af, bf, acc);
        }
        const float b1 = p.eb1[n0 + l15];
#pragma unroll
        for (int r = 0; r < 4; ++r) {
            const float ev = fmaxf(acc[r] + b1, 0.f);
            e4[r] = ev;
            EbU[(quad * 4 + r) * HPAD + n0 + l15] = (__bf16)ev;  // all 16 rows (garbage ok)
        }
    }
    __syncthreads();

    // ---- P2: enc = tanh(e@EW2 + e + eb2) -> Hb row x*9+8, encS (EbU rows 8+x) ----
    // encS writes race with A reads of rows 8..13 by other waves, but those A rows feed
    // C rows 8..13 which are discarded by the xr<RB guard — benign.
    {
        const int n0 = w * 16;
        f32x4 acc = {0, 0, 0, 0};
#pragma unroll
        for (int ks = 0; ks < 2; ++ks) {
            const int kk = ks * 32 + quad * 8;
            const bf16x8 af = *(const bf16x8*)(EbU + l15 * HPAD + kk);
            const bf16x8 bf = *(const bf16x8*)(ws + OFF_EW2 + (size_t)(n0 + l15) * 64 + kk);
            acc = MFMA16(af, bf, acc);
        }
        const float b2 = p.eb2[n0 + l15];
#pragma unroll
        for (int r = 0; r < 4; ++r) {
            const int xr = quad * 4 + r;
            if (xr < RB) {
                const float ev = tanhf(acc[r] + e4[r] + b2);
                Hb[(xr * 9 + 8) * HPAD + n0 + l15] = (__bf16)ev;
                EbU[(8 + xr) * HPAD + n0 + l15] = (__bf16)ev;   // encS, read at P8b
            }
        }
    }
    __syncthreads();

    // ---- P3: Q,K projections; wave w owns M-window w; Q,K share the af reads ----
    {
        f32x4 aq[4] = {{0,0,0,0},{0,0,0,0},{0,0,0,0},{0,0,0,0}};
        f32x4 ak[4] = {{0,0,0,0},{0,0,0,0},{0,0,0,0},{0,0,0,0}};
#pragma unroll
        for (int ks = 0; ks < 2; ++ks) {
            const int kk = ks * 32 + quad * 8;
            const bf16x8 af = *(const bf16x8*)(Hb + (w * 16 + l15) * HPAD + kk);
#pragma unroll
            for (int nt = 0; nt < 4; ++nt) {
                aq[nt] = MFMA16(af, *(const bf16x8*)(ws + OFF_WQ + (size_t)(nt * 16 + l15) * 64 + kk), aq[nt]);
                ak[nt] = MFMA16(af, *(const bf16x8*)(ws + OFF_WK + (size_t)(nt * 16 + l15) * 64 + kk), ak[nt]);
            }
        }
#pragma unroll
        for (int nt = 0; nt < 4; ++nt) {
            const float bq = p.bq[nt * 16 + l15], bk = p.bk[nt * 16 + l15];
#pragma unroll
            for (int r = 0; r < 4; ++r) {
                const int row = w * 16 + quad * 4 + r;
                Qb[row * HPAD + nt * 16 + l15] = (__bf16)(aq[nt][r] + bq);
                Kb[row * HPAD + nt * 16 + l15] = (__bf16)(ak[nt][r] + bk);
            }
        }
    }
    __syncthreads();

    // ---- P4+P5 (group-local): softmax -> attP (12-float rows), ah = att @ h -> Kb ----
    for (int xi = 0; xi < 2; ++xi) {
        const int x = w * 2 + xi;
        if (x >= RB) continue;
        {
            const int arow = (x * 9 + l15) * HPAD;
            f32x4 acc = {0, 0, 0, 0};
#pragma unroll
            for (int ks = 0; ks < 2; ++ks) {
                const int kk = ks * 32 + quad * 8;
                const bf16x8 qa = *(const bf16x8*)(Qb + arow + kk);
                const bf16x8 kb = *(const bf16x8*)(Kb + arow + kk);
                acc = MFMA16(qa, kb, acc);
            }
#pragma unroll
            for (int r = 0; r < 4; ++r) {
                const int i = quad * 4 + r;
                float s = (l15 < 9) ? acc[r] * 0.125f : -3.0e38f;
                float m = s;
#pragma unroll
                for (int off = 1; off < 16; off <<= 1) m = fmaxf(m, __shfl_xor(m, off, 64));
                float e = (l15 < 9) ? __expf(s - m) : 0.f;
                float sum = e;
#pragma unroll
                for (int off = 1; off < 16; off <<= 1) sum += __shfl_xor(sum, off, 64);
                const float pv = e / sum;
                if (i < 9 && l15 < 9) attU[x * 108 + i * 12 + l15] = pv;
            }
        }
        // ah: att rows via 2x float4 + 1 scalar (wave-uniform broadcast reads)
        {
            float vreg[9];
#pragma unroll
            for (int jj = 0; jj < 9; ++jj) vreg[jj] = (float)Hb[(x * 9 + jj) * HPAD + lane];
#pragma unroll
            for (int i = 0; i < 9; ++i) {
                const float4 a0 = *(const float4*)(attU + x * 108 + i * 12);
                const float4 a1 = *(const float4*)(attU + x * 108 + i * 12 + 4);
                const float a8 = attU[x * 108 + i * 12 + 8];
                const float a = a0.x * vreg[0] + a0.y * vreg[1] + a0.z * vreg[2] + a0.w * vreg[3]
                              + a1.x * vreg[4] + a1.y * vreg[5] + a1.z * vreg[6] + a1.w * vreg[7]
                              + a8 * vreg[8];
                Kb[(x * 9 + i) * HPAD + lane] = (__bf16)a;
            }
        }
    }
    __syncthreads();

    // ---- wave-local chain (no internal barriers): attv -> LN1 -> FFN1 -> LN2 ----
    // P6a: attv = ah @ wv + bv -> Qb (wave-own M-window)
    {
        f32x4 acc[4] = {{0,0,0,0},{0,0,0,0},{0,0,0,0},{0,0,0,0}};
#pragma unroll
        for (int ks = 0; ks < 2; ++ks) {
            const int kk = ks * 32 + quad * 8;
            const bf16x8 af = *(const bf16x8*)(Kb + (w * 16 + l15) * HPAD + kk);
#pragma unroll
            for (int nt = 0; nt < 4; ++nt)
                acc[nt] = MFMA16(af, *(const bf16x8*)(ws + OFF_WV + (size_t)(nt * 16 + l15) * 64 + kk), acc[nt]);
        }
#pragma unroll
        for (int nt = 0; nt < 4; ++nt) {
            const float bv = p.bv[nt * 16 + l15];
#pragma unroll
            for (int r = 0; r < 4; ++r)
                Qb[(w * 16 + quad * 4 + r) * HPAD + nt * 16 + l15] = (__bf16)(acc[nt][r] + bv);
        }
    }
    // P6b: o-proj + residual(h) + LN1 -> h2 in Hb (wave-local)
    proj_ln4(Qb, ws + OFF_WO, p.bo, p.l1g, p.l1b, Hb, w, quad, l15);
    // P7: FFN1: f = relu(h2@W1 + b1) -> Kb (wave-local)
    {
        f32x4 acc[4] = {{0,0,0,0},{0,0,0,0},{0,0,0,0},{0,0,0,0}};
#pragma unroll
        for (int ks = 0; ks < 2; ++ks) {
            const int kk = ks * 32 + quad * 8;
            const bf16x8 af = *(const bf16x8*)(Hb + (w * 16 + l15) * HPAD + kk);
#pragma unroll
            for (int nt = 0; nt < 4; ++nt)
                acc[nt] = MFMA16(af, *(const bf16x8*)(ws + OFF_F1 + (size_t)(nt * 16 + l15) * 64 + kk), acc[nt]);
        }
#pragma unroll
        for (int nt = 0; nt < 4; ++nt) {
            const float fb = p.fb1[nt * 16 + l15];
#pragma unroll
            for (int r = 0; r < 4; ++r)
                Kb[(w * 16 + quad * 4 + r) * HPAD + nt * 16 + l15] = (__bf16)fmaxf(acc[nt][r] + fb, 0.f);
        }
    }
    // P8: FFN2 + residual(h2) + LN2 -> h3 in Hb (wave-local)
    proj_ln4(Kb, ws + OFF_F2, p.fb2, p.l2g, p.l2b, Hb, w, quad, l15);
    __syncthreads();

    // ---- P8b + P9 (read-only on Hb) ----
    // P8b: ensB = [enc (from encS) | mean over 8 heads of h3] -> Kb
    {
#pragma unroll
        for (int it = 0; it < 2; ++it) {
            const int u = it * 256 + t;
            if (u < 384) {
                const int x = u >> 6, col = u & 63;
                float s = 0.f;
#pragma unroll
                for (int i = 0; i < 8; ++i) s += (float)Hb[(x * 9 + i) * HPAD + col];
                ensB[x * 136 + 64 + col] = (__bf16)(s * 0.125f);
                ensB[x * 136 + col] = EbU[(8 + x) * HPAD + col];
            }
        }
    }
    // P9: ni = sigmoid(LN7(h3[:, :8]@fc2ni + nib)) via MFMA (2 jobs/wave)
    for (int jn = 0; jn < 2; ++jn) {
        const int n = w * 2 + jn;
        const int l15c = (l15 < RB) ? l15 : (RB - 1);   // clamp garbage A rows in-bounds
        f32x4 acc = {0, 0, 0, 0};
#pragma unroll
        for (int ks = 0; ks < 2; ++ks) {
            const int kk = ks * 32 + quad * 8;
            const bf16x8 af = *(const bf16x8*)(Hb + (l15c * 9 + n) * HPAD + kk);
            const bf16x8 bf = *(const bf16x8*)(ws + OFF_NI + n * 1024 + (size_t)l15 * 64 + kk);
            acc = MFMA16(af, bf, acc);
        }
#pragma unroll
        for (int r = 0; r < 4; ++r) {
            const int x = quad * 4 + r;
            const float av = (l15 < 7) ? (acc[r] + p.nib[n * 7 + l15]) : 0.f;
            float s1 = av;
            s1 += __shfl_xor(s1, 1, 64); s1 += __shfl_xor(s1, 2, 64);
            s1 += __shfl_xor(s1, 4, 64); s1 += __shfl_xor(s1, 8, 64);
            const float mu = s1 * (1.f / 7.f);
            float d0 = (l15 < 7) ? (av - mu) : 0.f;
            float s2 = d0 * d0;
            s2 += __shfl_xor(s2, 1, 64); s2 += __shfl_xor(s2, 2, 64);
            s2 += __shfl_xor(s2, 4, 64); s2 += __shfl_xor(s2, 8, 64);
            const float rs = rsqrtf(s2 * (1.f / 7.f) + 1e-5f);
            if (x < RB && l15 < 7) {
                const float vv = (av - mu) * rs * p.ng[l15] + p.nb[l15];
                sNiP[(x * 8 + n) * 7 + l15] = 1.f / (1.f + __expf(-vv));
            }
        }
    }
    __syncthreads();

    // ---- P9b (+q_ni fused via 8-lane shfl) + P10s1 (disjoint LDS) ----
    {
#pragma unroll
        for (int it = 0; it < 2; ++it) {
            const int u = it * 256 + t;
            if (u < 384) {
                const int x = u >> 6, rem = u & 63, i = rem >> 3, jj = rem & 7;
                const float nf = (i == jj) ? 1.f : sNiP[(x * 8 + i) * 7 + jj - (jj > i ? 1 : 0)];
                const int bt = bt0 + x;
                const size_t btc = (bt < ROWSG) ? bt : (ROWSG - 1);
                if (bt < ROWSG) {
                    p.out[NN_OFF + (size_t)bt * 64 + rem] = nf;
                    p.out[EYE_OFF + (size_t)bt * 64 + rem] = (i == jj) ? 1.f : 0.f;
                }
                float s = p.qvals[btc * 8 + jj] * nf;
                s += __shfl_xor(s, 1, 64); s += __shfl_xor(s, 2, 64); s += __shfl_xor(s, 4, 64);
                if (jj == 0) qniL[x * 8 + i] = s;
            }
        }
    }
    // P10s1: t1 = relu(ens@w1a+b1a) -> Tb1(EbU); t2 = relu(ens@w2a+b2a) -> Tb2; shared af
    {
        const int n0 = w * 16;
        f32x4 ac1 = {0,0,0,0}, ac2 = {0,0,0,0};
#pragma unroll
        for (int ks = 0; ks < 4; ++ks) {
            const int kk = ks * 32 + quad * 8;
            const bf16x8 af = *(const bf16x8*)(ensB + l15 * 136 + kk);
            ac1 = MFMA16(af, *(const bf16x8*)(ws + OFF_W1A + (size_t)(n0 + l15) * 128 + kk), ac1);
            ac2 = MFMA16(af, *(const bf16x8*)(ws + OFF_W2A + (size_t)(n0 + l15) * 128 + kk), ac2);
        }
        const float b1 = p.b1a[n0 + l15], b2 = p.b2a[n0 + l15];
#pragma unroll
        for (int r = 0; r < 4; ++r) {
            EbU[(quad * 4 + r) * HPAD + n0 + l15] = (__bf16)fmaxf(ac1[r] + b1, 0.f);
            Tb2[(quad * 4 + r) * HPAD + n0 + l15] = (__bf16)fmaxf(ac2[r] + b2, 0.f);
        }
    }
    __syncthreads();

    // ---- P10s2: w1 (wave w owns 4 n-tiles, shared af) + 6 small jobs ----
    {
        f32x4 acc[4] = {{0,0,0,0},{0,0,0,0},{0,0,0,0},{0,0,0,0}};
#pragma unroll
        for (int ks = 0; ks < 2; ++ks) {
            const int kk = ks * 32 + quad * 8;
            const bf16x8 af = *(const bf16x8*)(EbU + l15 * HPAD + kk);
#pragma unroll
            for (int nt = 0; nt < 4; ++nt) {
                const int n0 = (w * 4 + nt) * 16;
                acc[nt] = MFMA16(af, *(const bf16x8*)(ws + OFF_W1B + (size_t)(n0 + l15) * 64 + kk), acc[nt]);
            }
        }
#pragma unroll
        for (int nt = 0; nt < 4; ++nt) {
            const int n0 = (w * 4 + nt) * 16;
            const float bb = p.b1b[n0 + l15];
#pragma unroll
            for (int r = 0; r < 4; ++r) {
                const int xr = quad * 4 + r;
                if (xr < RB) W1bS[xr * 256 + n0 + l15] = (__bf16)fabsf(acc[nt][r] + bb);
            }
        }
    }
#pragma unroll
    for (int it = 0; it < 2; ++it) {
        const int j = w + 4 * it;
        if (j >= 6) continue;
        // j 0,1 -> b1 (ensB@HB1W); j 2,3 -> w2 (Tb2@W2B); j 4,5 -> t3 (ensB@HB2W1)
        const int mode = (j < 2) ? 1 : (j < 4) ? 2 : 3;
        const int n0 = (j & 1) * 16;
        const __bf16* A  = (mode == 2) ? Tb2 : ensB;
        const int aStride = (mode == 2) ? HPAD : 136;
        const __bf16* WT = ws + ((mode == 1) ? OFF_HB1W : (mode == 2) ? OFF_W2B : OFF_HB2W1);
        const float* bias = (mode == 1) ? p.hb1b : (mode == 2) ? p.b2b : p.hb2b1;
        const int Kp = (mode == 2) ? 64 : 128;
        const int ksteps = (mode == 2) ? 2 : 4;
        f32x4 acc = {0, 0, 0, 0};
        for (int ks = 0; ks < ksteps; ++ks) {
            const int kk = ks * 32 + quad * 8;
            const bf16x8 af = *(const bf16x8*)(A + l15 * aStride + kk);
            const bf16x8 bf = *(const bf16x8*)(WT + (size_t)(n0 + l15) * Kp + kk);
            acc = MFMA16(af, bf, acc);
        }
        const float bb = bias[n0 + l15];
#pragma unroll
        for (int r = 0; r < 4; ++r) {
            const int xr = quad * 4 + r;
            if (xr < RB) {
                const float val = acc[r] + bb;
                if (mode == 1)      B1f[xr * 32 + n0 + l15] = val;
                else if (mode == 2) W2f[xr * 32 + n0 + l15] = fabsf(val);
                else                T3f[xr * 32 + n0 + l15] = fmaxf(val, 0.f);
            }
        }
    }
    __syncthreads();

    // ---- P11: hidden = elu(q_ni@w1 + b1); y = hidden@w2 + t3@hw2 + hb2b2 ----
    if (t < 96) {
        const int x = t >> 4, sub = t & 15;
        float pp = 0.f, pb = 0.f;
#pragma unroll
        for (int h2i = 0; h2i < 2; ++h2i) {
            const int e = sub + h2i * 16;
            float a = B1f[x * 32 + e];
#pragma unroll
            for (int i = 0; i < 8; ++i) a += qniL[x * 8 + i] * (float)W1bS[x * 256 + i * 32 + e];
            const float hid = a > 0.f ? a : (__expf(a) - 1.f);
            pp += hid * W2f[x * 32 + e];
            pb += T3f[x * 32 + e] * p.hw2[e];
        }
#pragma unroll
        for (int off = 1; off < 16; off <<= 1) {
            pp += __shfl_xor(pp, off, 64);
            pb += __shfl_xor(pb, off, 64);
        }
        const int bt = bt0 + x;
        if (sub == 0 && bt < ROWSG) p.out[bt] = pp + pb + p.hb2b2[0];
    }
}

extern "C" void kernel_launch(void* const* d_in, const int* in_sizes, int n_in,
                              void* d_out, int out_size, void* d_ws, size_t ws_size,
                              hipStream_t stream) {
    TP tp;
    tp.src[0]  = (const float*)d_in[3];   // enc_w1
    tp.src[1]  = (const float*)d_in[5];   // enc_w2
    tp.src[2]  = (const float*)d_in[7];   // wq
    tp.src[3]  = (const float*)d_in[9];   // wk
    tp.src[4]  = (const float*)d_in[11];  // wv
    tp.src[5]  = (const float*)d_in[13];  // wo
    tp.src[6]  = (const float*)d_in[17];  // ffn_w1
    tp.src[7]  = (const float*)d_in[19];  // ffn_w2
    tp.src[8]  = (const float*)d_in[27];  // w1a
    tp.src[9]  = (const float*)d_in[29];  // w1b
    tp.src[10] = (const float*)d_in[31];  // hb1w
    tp.src[11] = (const float*)d_in[33];  // w2a
    tp.src[12] = (const float*)d_in[35];  // w2b
    tp.src[13] = (const float*)d_in[37];  // hb2w1
    tp.src[14] = (const float*)d_in[23];  // fc2ni_w
    wtrans<<<(WS_TOTAL + 255) / 256, 256, 0, stream>>>(tp);

    MainP p;
    p.qvals = (const float*)d_in[0];
    p.states = (const float*)d_in[1];
    p.hid = (const float*)d_in[2];
    p.eb1 = (const float*)d_in[4];
    p.eb2 = (const float*)d_in[6];
    p.bq = (const float*)d_in[8];
    p.bk = (const float*)d_in[10];
    p.bv = (const float*)d_in[12];
    p.bo = (const float*)d_in[14];
    p.l1g = (const float*)d_in[15];
    p.l1b = (const float*)d_in[16];
    p.fb1 = (const float*)d_in[18];
    p.fb2 = (const float*)d_in[20];
    p.l2g = (const float*)d_in[21];
    p.l2b = (const float*)d_in[22];
    p.niw = (const float*)d_in[23];
    p.nib = (const float*)d_in[24];
    p.ng = (const float*)d_in[25];
    p.nb = (const float*)d_in[26];
    p.b1a = (const float*)d_in[28];
    p.b1b = (const float*)d_in[30];
    p.hb1b = (const float*)d_in[32];
    p.b2a = (const float*)d_in[34];
    p.b2b = (const float*)d_in[36];
    p.hb2b1 = (const float*)d_in[38];
    p.hw2 = (const float*)d_in[39];
    p.hb2b2 = (const float*)d_in[40];
    p.out = (float*)d_out;

    mixer_main<<<NBLK, 256, 0, stream>>>(p);
}

// Round 7
// 430.201 us; speedup vs baseline: 1.0566x; 1.0566x over previous
//
#include <hip/hip_runtime.h>
#include <hip/hip_bf16.h>

typedef __bf16 bf16x8 __attribute__((ext_vector_type(8)));
typedef __bf16 bf16x4 __attribute__((ext_vector_type(4)));
typedef float f32x4 __attribute__((ext_vector_type(4)));

#define ROWSG 32768          // B*T
#define RB 6                 // bt rows per block -> 54 valid + 10 pad = 64 supertile rows
#define NBLK 5462            // ceil(32768/6)
#define HPAD 72              // bf16 row stride
#define NN_OFF ((size_t)ROWSG)
#define EYE_OFF ((size_t)ROWSG + (size_t)ROWSG*64)

// weight-cache offsets (bf16 elements), all WT[n][k] row-major, stride = Kp
#define OFF_EW1   0          // 64 x 224 (K=200 zero-padded)
#define OFF_EW2   14336      // 64 x 64
#define OFF_WQ    18432
#define OFF_WK    22528
#define OFF_WV    26624
#define OFF_WO    30720
#define OFF_F1    34816
#define OFF_F2    38912
#define OFF_W1A   43008      // 64 x 128
#define OFF_W1B   51200      // 256 x 64
#define OFF_HB1W  67584      // 32 x 128
#define OFF_W2A   71680      // 64 x 128
#define OFF_W2B   79872      // 32 x 64
#define OFF_HB2W1 81920      // 32 x 128
#define OFF_NI    86016      // 8 mats x 16(e-pad) x 64 bf16 = 8192  (fc2ni transposed)
#define WS_TOTAL  94208

__device__ __align__(16) __bf16 g_ws[WS_TOTAL];

#define MFMA16(a,b,c) __builtin_amdgcn_mfma_f32_16x16x32_bf16(a,b,c,0,0,0)

// ---------------- weight transform kernel ----------------
struct TP { const float* src[15]; };

__global__ __launch_bounds__(256) void wtrans(TP tp) {
    const int gid = blockIdx.x * 256 + threadIdx.x;
    if (gid >= WS_TOTAL) return;
    if (gid >= OFF_NI) {
        // fc2ni [n][d][e] (8,64,7) -> [n][e'][d], e' padded to 16 with zeros
        const int loc = gid - OFF_NI;
        const int nmat = loc >> 10, rem = loc & 1023, e = rem >> 6, k = rem & 63;
        float v = (e < 7) ? tp.src[14][nmat * 448 + k * 7 + e] : 0.f;
        g_ws[gid] = (__bf16)v;
        return;
    }
    const int OFFS[14] = {OFF_EW1, OFF_EW2, OFF_WQ, OFF_WK, OFF_WV, OFF_WO, OFF_F1,
                          OFF_F2, OFF_W1A, OFF_W1B, OFF_HB1W, OFF_W2A, OFF_W2B, OFF_HB2W1};
    const int KPS[14]  = {224, 64, 64, 64, 64, 64, 64, 64, 128, 64, 128, 128, 64, 128};
    const int KRS[14]  = {200, 64, 64, 64, 64, 64, 64, 64, 128, 64, 128, 128, 64, 128};
    const int NS[14]   = {64, 64, 64, 64, 64, 64, 64, 64, 64, 256, 32, 64, 32, 32};
    int m = 0;
#pragma unroll
    for (int i = 1; i < 14; ++i) if (gid >= OFFS[i]) m = i;
    const int loc = gid - OFFS[m];
    const int Kp = KPS[m];
    const int n = loc / Kp;
    const int k = loc - n * Kp;
    float v = 0.f;
    if (k < KRS[m]) v = tp.src[m][(size_t)k * NS[m] + n];   // src is W[k][n]
    g_ws[gid] = (__bf16)v;
}

// ---------------- main fused kernel ----------------
struct MainP {
    const float *qvals, *states, *hid, *eb1, *eb2, *bq, *bk, *bv, *bo,
        *l1g, *l1b, *fb1, *fb2, *l2g, *l2b, *niw, *nib, *ng, *nb,
        *b1a, *b1b, *hb1b, *b2a, *b2b, *hb2b1, *hw2, *hb2b2;
    float* out;
};

// projection + bias + residual + LayerNorm over the 64-row supertile; wave w owns M-window w.
__device__ __forceinline__ void proj_ln4(const __bf16* A, const __bf16* WT,
                                         const float* bias, const float* g, const float* bb,
                                         __bf16* H, int w, int quad, int l15) {
    const int mt = w;
    f32x4 acc0 = {0,0,0,0}, acc1 = {0,0,0,0}, acc2 = {0,0,0,0}, acc3 = {0,0,0,0};
#pragma unroll
    for (int ks = 0; ks < 2; ++ks) {
        const int kk = ks * 32 + quad * 8;
        const bf16x8 af = *(const bf16x8*)(A + (mt * 16 + l15) * HPAD + kk);
        acc0 = MFMA16(af, *(const bf16x8*)(WT + (size_t)(0 * 16 + l15) * 64 + kk), acc0);
        acc1 = MFMA16(af, *(const bf16x8*)(WT + (size_t)(1 * 16 + l15) * 64 + kk), acc1);
        acc2 = MFMA16(af, *(const bf16x8*)(WT + (size_t)(2 * 16 + l15) * 64 + kk), acc2);
        acc3 = MFMA16(af, *(const bf16x8*)(WT + (size_t)(3 * 16 + l15) * 64 + kk), acc3);
    }
    float v[4][4], g4[4], b4[4];
#pragma unroll
    for (int nt = 0; nt < 4; ++nt) {
        const int col = nt * 16 + l15;
        const float bo = bias[col];
        g4[nt] = g[col]; b4[nt] = bb[col];
        const f32x4 a = (nt == 0) ? acc0 : (nt == 1) ? acc1 : (nt == 2) ? acc2 : acc3;
#pragma unroll
        for (int r = 0; r < 4; ++r)
            v[nt][r] = a[r] + bo + (float)H[(mt * 16 + quad * 4 + r) * HPAD + col];
    }
#pragma unroll
    for (int r = 0; r < 4; ++r) {
        float s  = v[0][r] + v[1][r] + v[2][r] + v[3][r];
        float s2 = v[0][r]*v[0][r] + v[1][r]*v[1][r] + v[2][r]*v[2][r] + v[3][r]*v[3][r];
#pragma unroll
        for (int off = 1; off < 16; off <<= 1) {
            s  += __shfl_xor(s,  off, 64);
            s2 += __shfl_xor(s2, off, 64);
        }
        const float mu  = s * 0.015625f;
        const float var = s2 * 0.015625f - mu * mu;
        const float rs  = rsqrtf(var + 1e-5f);
#pragma unroll
        for (int nt = 0; nt < 4; ++nt)
            H[(mt * 16 + quad * 4 + r) * HPAD + nt * 16 + l15] =
                (__bf16)((v[nt][r] - mu) * rs * g4[nt] + b4[nt]);
    }
}

// RB=6 supertile (64 rows), wave w owns M-window w in all 64-row GEMM phases.
// 9 barriers. VGPR discipline: never hold two accumulator banks live at once —
// 72 VGPR (R5) dropped the HW wave tier (m69: cliffs at 64/128) and cost a block/CU.
__global__ __launch_bounds__(256) void mixer_main(MainP p) {
    __shared__ __align__(16) __bf16 Hb[64 * HPAD];   // h -> h2 -> h3              (9216 B)
    __shared__ __align__(16) __bf16 Qb[64 * HPAD];   // Sb | q/attv | tail scratch (9216 B)
    __shared__ __align__(16) __bf16 Kb[64 * HPAD];   // k -> ah -> ffn hid | ensB  (9216 B)
    __shared__ __align__(16) __bf16 EbU[16 * HPAD];  // e | encS(rows 8..13) | Tb1 (2304 B)
    __shared__ __align__(16) float  attU[6 * 108];   // att probs, 12-float rows   (2592 B)
    // total 32544 B -> 5 blocks/CU

    // aliases into Qb (disjoint lifetimes)
    __bf16* Sb   = Qb;                       // 6x224 bf16 = 2688B      [P0..P1]
    __bf16* W1bS = Qb;                       // 6x256 bf16 = 3072B      [P10s2..P11]
    float*  B1f  = (float*)(Qb + 1536);      // @3072B..3840B
    float*  W2f  = (float*)(Qb + 1920);      // @3840B..4608B
    float*  T3f  = (float*)(Qb + 2304);      // @4608B..5376B
    __bf16* Tb2  = Qb + 2688;                // @5376B..7680B, 16x72    [P10s1..P10s2]
    float*  sNiP = (float*)(Qb + 3840);      // @7680B..9024B, 336 f32  [P9..P9b]
    float*  qniL = (float*)(Qb + 4512);      // @9024B..9216B, 48 f32   [P9b..P11]
    __bf16* ensB = Kb;                       // 6x136 bf16 = 1632B      [P8b..P10s2]

    const int blk = blockIdx.x;
    const int bt0 = blk * RB;
    const int t = threadIdx.x;
    const int w = t >> 6, lane = t & 63, quad = lane >> 4, l15 = lane & 15;
    const __bf16* ws = g_ws;

    // ---- P0: stage hidden_state -> Hb; states -> Sb ----
#pragma unroll
    for (int it = 0; it < 3; ++it) {
        const int u = it * 256 + t;               // 768 float4 units = 6 rows x 512 floats
        const int x = u >> 7, rem = u & 127, n = rem >> 4, d4 = (rem & 15) * 4;
        const int bt = bt0 + x;
        const size_t btc = (bt < ROWSG) ? bt : (ROWSG - 1);
        const float4 v4 = *(const float4*)(p.hid + (btc * 512 + n * 64 + d4));
        bf16x4 o; o[0] = (__bf16)v4.x; o[1] = (__bf16)v4.y; o[2] = (__bf16)v4.z; o[3] = (__bf16)v4.w;
        *(bf16x4*)(Hb + (x * 9 + n) * HPAD + d4) = o;
    }
#pragma unroll
    for (int it = 0; it < 2; ++it) {
        const int u = it * 256 + t;               // 300 float4 units = 6 rows x 200 floats
        if (u < 300) {
            const int xr = u / 50, c4 = u - xr * 50;
            const int bt = bt0 + xr;
            const size_t btc = (bt < ROWSG) ? bt : (ROWSG - 1);
            const float4 v4 = *(const float4*)(p.states + btc * 200 + c4 * 4);
            bf16x4 o; o[0] = (__bf16)v4.x; o[1] = (__bf16)v4.y; o[2] = (__bf16)v4.z; o[3] = (__bf16)v4.w;
            *(bf16x4*)(Sb + xr * 224 + c4 * 4) = o;
        }
    }
    if (t < 144) { const int xr = t / 24, c = t - xr * 24; Sb[xr * 224 + 200 + c] = (__bf16)0.0f; }
    __syncthreads();

    // ---- P1: e = relu(S @ EW1 + eb1); row clamp for garbage A rows ----
    float e4[4];
    {
        const int n0 = w * 16;
        const int srow = (l15 < RB) ? l15 : (RB - 1);
        f32x4 acc = {0, 0, 0, 0};
        for (int ks = 0; ks < 7; ++ks) {
            const int kk = ks * 32 + quad * 8;
            const bf16x8 af = *(const bf16x8*)(Sb + srow * 224 + kk);
            const bf16x8 bf = *(const bf16x8*)(ws + OFF_EW1 + (size_t)(n0 + l15) * 224 + kk);
            acc = MFMA16(af, bf, acc);
        }
        const float b1 = p.eb1[n0 + l15];
#pragma unroll
        for (int r = 0; r < 4; ++r) {
            const float ev = fmaxf(acc[r] + b1, 0.f);
            e4[r] = ev;
            EbU[(quad * 4 + r) * HPAD + n0 + l15] = (__bf16)ev;  // all 16 rows (garbage ok)
        }
    }
    __syncthreads();

    // ---- P2: enc = tanh(e@EW2 + e + eb2) -> Hb row x*9+8, encS (EbU rows 8+x) ----
    // encS writes race with A reads of rows 8..13 by other waves, but those A rows feed
    // C rows 8..13 which are discarded by the xr<RB guard — benign.
    {
        const int n0 = w * 16;
        f32x4 acc = {0, 0, 0, 0};
#pragma unroll
        for (int ks = 0; ks < 2; ++ks) {
            const int kk = ks * 32 + quad * 8;
            const bf16x8 af = *(const bf16x8*)(EbU + l15 * HPAD + kk);
            const bf16x8 bf = *(const bf16x8*)(ws + OFF_EW2 + (size_t)(n0 + l15) * 64 + kk);
            acc = MFMA16(af, bf, acc);
        }
        const float b2 = p.eb2[n0 + l15];
#pragma unroll
        for (int r = 0; r < 4; ++r) {
            const int xr = quad * 4 + r;
            if (xr < RB) {
                const float ev = tanhf(acc[r] + e4[r] + b2);
                Hb[(xr * 9 + 8) * HPAD + n0 + l15] = (__bf16)ev;
                EbU[(8 + xr) * HPAD + n0 + l15] = (__bf16)ev;   // encS, read at P8b
            }
        }
    }
    __syncthreads();

    // ---- P3: Q,K projections; wave w owns M-window w; two SEQUENTIAL 4-acc banks ----
    // (unroll 1: forbid re-fusing the banks — 8 simultaneous f32x4 accs was the R5
    //  VGPR-72 regression; re-reading 2 af fragments per bank is far cheaper)
#pragma unroll 1
    for (int mat = 0; mat < 2; ++mat) {
        const __bf16* wt = ws + (mat == 0 ? OFF_WQ : OFF_WK);
        const float* bias = (mat == 0 ? p.bq : p.bk);
        __bf16* dst = (mat == 0 ? Qb : Kb);
        f32x4 acc[4] = {{0,0,0,0},{0,0,0,0},{0,0,0,0},{0,0,0,0}};
#pragma unroll
        for (int ks = 0; ks < 2; ++ks) {
            const int kk = ks * 32 + quad * 8;
            const bf16x8 af = *(const bf16x8*)(Hb + (w * 16 + l15) * HPAD + kk);
#pragma unroll
            for (int nt = 0; nt < 4; ++nt)
                acc[nt] = MFMA16(af, *(const bf16x8*)(wt + (size_t)(nt * 16 + l15) * 64 + kk), acc[nt]);
        }
#pragma unroll
        for (int nt = 0; nt < 4; ++nt) {
            const float bv = bias[nt * 16 + l15];
#pragma unroll
            for (int r = 0; r < 4; ++r)
                dst[(w * 16 + quad * 4 + r) * HPAD + nt * 16 + l15] = (__bf16)(acc[nt][r] + bv);
        }
    }
    __syncthreads();

    // ---- P4+P5 (group-local): softmax -> attP (12-float rows), ah = att @ h -> Kb ----
    for (int xi = 0; xi < 2; ++xi) {
        const int x = w * 2 + xi;
        if (x >= RB) continue;
        {
            const int arow = (x * 9 + l15) * HPAD;
            f32x4 acc = {0, 0, 0, 0};
#pragma unroll
            for (int ks = 0; ks < 2; ++ks) {
                const int kk = ks * 32 + quad * 8;
                const bf16x8 qa = *(const bf16x8*)(Qb + arow + kk);
                const bf16x8 kb = *(const bf16x8*)(Kb + arow + kk);
                acc = MFMA16(qa, kb, acc);
            }
#pragma unroll
            for (int r = 0; r < 4; ++r) {
                const int i = quad * 4 + r;
                float s = (l15 < 9) ? acc[r] * 0.125f : -3.0e38f;
                float m = s;
#pragma unroll
                for (int off = 1; off < 16; off <<= 1) m = fmaxf(m, __shfl_xor(m, off, 64));
                float e = (l15 < 9) ? __expf(s - m) : 0.f;
                float sum = e;
#pragma unroll
                for (int off = 1; off < 16; off <<= 1) sum += __shfl_xor(sum, off, 64);
                const float pv = e / sum;
                if (i < 9 && l15 < 9) attU[x * 108 + i * 12 + l15] = pv;
            }
        }
        // ah: att rows via 2x float4 + 1 scalar (wave-uniform broadcast reads)
        {
            float vreg[9];
#pragma unroll
            for (int jj = 0; jj < 9; ++jj) vreg[jj] = (float)Hb[(x * 9 + jj) * HPAD + lane];
#pragma unroll
            for (int i = 0; i < 9; ++i) {
                const float4 a0 = *(const float4*)(attU + x * 108 + i * 12);
                const float4 a1 = *(const float4*)(attU + x * 108 + i * 12 + 4);
                const float a8 = attU[x * 108 + i * 12 + 8];
                const float a = a0.x * vreg[0] + a0.y * vreg[1] + a0.z * vreg[2] + a0.w * vreg[3]
                              + a1.x * vreg[4] + a1.y * vreg[5] + a1.z * vreg[6] + a1.w * vreg[7]
                              + a8 * vreg[8];
                Kb[(x * 9 + i) * HPAD + lane] = (__bf16)a;
            }
        }
    }
    __syncthreads();

    // ---- wave-local chain (no internal barriers): attv -> LN1 -> FFN1 -> LN2 ----
    // P6a: attv = ah @ wv + bv -> Qb (wave-own M-window)
    {
        f32x4 acc[4] = {{0,0,0,0},{0,0,0,0},{0,0,0,0},{0,0,0,0}};
#pragma unroll
        for (int ks = 0; ks < 2; ++ks) {
            const int kk = ks * 32 + quad * 8;
            const bf16x8 af = *(const bf16x8*)(Kb + (w * 16 + l15) * HPAD + kk);
#pragma unroll
            for (int nt = 0; nt < 4; ++nt)
                acc[nt] = MFMA16(af, *(const bf16x8*)(ws + OFF_WV + (size_t)(nt * 16 + l15) * 64 + kk), acc[nt]);
        }
#pragma unroll
        for (int nt = 0; nt < 4; ++nt) {
            const float bv = p.bv[nt * 16 + l15];
#pragma unroll
            for (int r = 0; r < 4; ++r)
                Qb[(w * 16 + quad * 4 + r) * HPAD + nt * 16 + l15] = (__bf16)(acc[nt][r] + bv);
        }
    }
    // P6b: o-proj + residual(h) + LN1 -> h2 in Hb (wave-local)
    proj_ln4(Qb, ws + OFF_WO, p.bo, p.l1g, p.l1b, Hb, w, quad, l15);
    // P7: FFN1: f = relu(h2@W1 + b1) -> Kb (wave-local)
    {
        f32x4 acc[4] = {{0,0,0,0},{0,0,0,0},{0,0,0,0},{0,0,0,0}};
#pragma unroll
        for (int ks = 0; ks < 2; ++ks) {
            const int kk = ks * 32 + quad * 8;
            const bf16x8 af = *(const bf16x8*)(Hb + (w * 16 + l15) * HPAD + kk);
#pragma unroll
            for (int nt = 0; nt < 4; ++nt)
                acc[nt] = MFMA16(af, *(const bf16x8*)(ws + OFF_F1 + (size_t)(nt * 16 + l15) * 64 + kk), acc[nt]);
        }
#pragma unroll
        for (int nt = 0; nt < 4; ++nt) {
            const float fb = p.fb1[nt * 16 + l15];
#pragma unroll
            for (int r = 0; r < 4; ++r)
                Kb[(w * 16 + quad * 4 + r) * HPAD + nt * 16 + l15] = (__bf16)fmaxf(acc[nt][r] + fb, 0.f);
        }
    }
    // P8: FFN2 + residual(h2) + LN2 -> h3 in Hb (wave-local)
    proj_ln4(Kb, ws + OFF_F2, p.fb2, p.l2g, p.l2b, Hb, w, quad, l15);
    __syncthreads();

    // ---- P8b + P9 (read-only on Hb) ----
    // P8b: ensB = [enc (from encS) | mean over 8 heads of h3] -> Kb
    {
#pragma unroll
        for (int it = 0; it < 2; ++it) {
            const int u = it * 256 + t;
            if (u < 384) {
                const int x = u >> 6, col = u & 63;
                float s = 0.f;
#pragma unroll
                for (int i = 0; i < 8; ++i) s += (float)Hb[(x * 9 + i) * HPAD + col];
                ensB[x * 136 + 64 + col] = (__bf16)(s * 0.125f);
                ensB[x * 136 + col] = EbU[(8 + x) * HPAD + col];
            }
        }
    }
    // P9: ni = sigmoid(LN7(h3[:, :8]@fc2ni + nib)) via MFMA (2 jobs/wave)
#pragma unroll 1
    for (int jn = 0; jn < 2; ++jn) {
        const int n = w * 2 + jn;
        const int l15c = (l15 < RB) ? l15 : (RB - 1);   // clamp garbage A rows in-bounds
        f32x4 acc = {0, 0, 0, 0};
#pragma unroll
        for (int ks = 0; ks < 2; ++ks) {
            const int kk = ks * 32 + quad * 8;
            const bf16x8 af = *(const bf16x8*)(Hb + (l15c * 9 + n) * HPAD + kk);
            const bf16x8 bf = *(const bf16x8*)(ws + OFF_NI + n * 1024 + (size_t)l15 * 64 + kk);
            acc = MFMA16(af, bf, acc);
        }
#pragma unroll
        for (int r = 0; r < 4; ++r) {
            const int x = quad * 4 + r;
            const float av = (l15 < 7) ? (acc[r] + p.nib[n * 7 + l15]) : 0.f;
            float s1 = av;
            s1 += __shfl_xor(s1, 1, 64); s1 += __shfl_xor(s1, 2, 64);
            s1 += __shfl_xor(s1, 4, 64); s1 += __shfl_xor(s1, 8, 64);
            const float mu = s1 * (1.f / 7.f);
            float d0 = (l15 < 7) ? (av - mu) : 0.f;
            float s2 = d0 * d0;
            s2 += __shfl_xor(s2, 1, 64); s2 += __shfl_xor(s2, 2, 64);
            s2 += __shfl_xor(s2, 4, 64); s2 += __shfl_xor(s2, 8, 64);
            const float rs = rsqrtf(s2 * (1.f / 7.f) + 1e-5f);
            if (x < RB && l15 < 7) {
                const float vv = (av - mu) * rs * p.ng[l15] + p.nb[l15];
                sNiP[(x * 8 + n) * 7 + l15] = 1.f / (1.f + __expf(-vv));
            }
        }
    }
    __syncthreads();

    // ---- P9b (+q_ni fused via 8-lane shfl) + P10s1 (disjoint LDS) ----
    {
#pragma unroll
        for (int it = 0; it < 2; ++it) {
            const int u = it * 256 + t;
            if (u < 384) {
                const int x = u >> 6, rem = u & 63, i = rem >> 3, jj = rem & 7;
                const float nf = (i == jj) ? 1.f : sNiP[(x * 8 + i) * 7 + jj - (jj > i ? 1 : 0)];
                const int bt = bt0 + x;
                const size_t btc = (bt < ROWSG) ? bt : (ROWSG - 1);
                if (bt < ROWSG) {
                    p.out[NN_OFF + (size_t)bt * 64 + rem] = nf;
                    p.out[EYE_OFF + (size_t)bt * 64 + rem] = (i == jj) ? 1.f : 0.f;
                }
                float s = p.qvals[btc * 8 + jj] * nf;
                s += __shfl_xor(s, 1, 64); s += __shfl_xor(s, 2, 64); s += __shfl_xor(s, 4, 64);
                if (jj == 0) qniL[x * 8 + i] = s;
            }
        }
    }
    // P10s1: t1 = relu(ens@w1a+b1a) -> Tb1(EbU); t2 = relu(ens@w2a+b2a) -> Tb2
    // (sequential banks, unroll 1: one f32x4 acc live at a time)
#pragma unroll 1
    for (int m2 = 0; m2 < 2; ++m2) {
        const __bf16* wt = ws + (m2 == 0 ? OFF_W1A : OFF_W2A);
        const float* bias = m2 == 0 ? p.b1a : p.b2a;
        __bf16* dst = m2 == 0 ? EbU : Tb2;
        const int n0 = w * 16;
        f32x4 acc = {0, 0, 0, 0};
#pragma unroll
        for (int ks = 0; ks < 4; ++ks) {
            const int kk = ks * 32 + quad * 8;
            const bf16x8 af = *(const bf16x8*)(ensB + l15 * 136 + kk);
            acc = MFMA16(af, *(const bf16x8*)(wt + (size_t)(n0 + l15) * 128 + kk), acc);
        }
        const float bb = bias[n0 + l15];
#pragma unroll
        for (int r = 0; r < 4; ++r)
            dst[(quad * 4 + r) * HPAD + n0 + l15] = (__bf16)fmaxf(acc[r] + bb, 0.f);
    }
    __syncthreads();

    // ---- P10s2: w1 (wave w owns 4 n-tiles, shared af) + 6 small jobs ----
    {
        f32x4 acc[4] = {{0,0,0,0},{0,0,0,0},{0,0,0,0},{0,0,0,0}};
#pragma unroll
        for (int ks = 0; ks < 2; ++ks) {
            const int kk = ks * 32 + quad * 8;
            const bf16x8 af = *(const bf16x8*)(EbU + l15 * HPAD + kk);
#pragma unroll
            for (int nt = 0; nt < 4; ++nt) {
                const int n0 = (w * 4 + nt) * 16;
                acc[nt] = MFMA16(af, *(const bf16x8*)(ws + OFF_W1B + (size_t)(n0 + l15) * 64 + kk), acc[nt]);
            }
        }
#pragma unroll
        for (int nt = 0; nt < 4; ++nt) {
            const int n0 = (w * 4 + nt) * 16;
            const float bb = p.b1b[n0 + l15];
#pragma unroll
            for (int r = 0; r < 4; ++r) {
                const int xr = quad * 4 + r;
                if (xr < RB) W1bS[xr * 256 + n0 + l15] = (__bf16)fabsf(acc[nt][r] + bb);
            }
        }
    }
#pragma unroll 1
    for (int it = 0; it < 2; ++it) {
        const int j = w + 4 * it;
        if (j >= 6) continue;
        // j 0,1 -> b1 (ensB@HB1W); j 2,3 -> w2 (Tb2@W2B); j 4,5 -> t3 (ensB@HB2W1)
        const int mode = (j < 2) ? 1 : (j < 4) ? 2 : 3;
        const int n0 = (j & 1) * 16;
        const __bf16* A  = (mode == 2) ? Tb2 : ensB;
        const int aStride = (mode == 2) ? HPAD : 136;
        const __bf16* WT = ws + ((mode == 1) ? OFF_HB1W : (mode == 2) ? OFF_W2B : OFF_HB2W1);
        const float* bias = (mode == 1) ? p.hb1b : (mode == 2) ? p.b2b : p.hb2b1;
        const int Kp = (mode == 2) ? 64 : 128;
        const int ksteps = (mode == 2) ? 2 : 4;
        f32x4 acc = {0, 0, 0, 0};
        for (int ks = 0; ks < ksteps; ++ks) {
            const int kk = ks * 32 + quad * 8;
            const bf16x8 af = *(const bf16x8*)(A + l15 * aStride + kk);
            const bf16x8 bf = *(const bf16x8*)(WT + (size_t)(n0 + l15) * Kp + kk);
            acc = MFMA16(af, bf, acc);
        }
        const float bb = bias[n0 + l15];
#pragma unroll
        for (int r = 0; r < 4; ++r) {
            const int xr = quad * 4 + r;
            if (xr < RB) {
                const float val = acc[r] + bb;
                if (mode == 1)      B1f[xr * 32 + n0 + l15] = val;
                else if (mode == 2) W2f[xr * 32 + n0 + l15] = fabsf(val);
                else                T3f[xr * 32 + n0 + l15] = fmaxf(val, 0.f);
            }
        }
    }
    __syncthreads();

    // ---- P11: hidden = elu(q_ni@w1 + b1); y = hidden@w2 + t3@hw2 + hb2b2 ----
    if (t < 96) {
        const int x = t >> 4, sub = t & 15;
        float pp = 0.f, pb = 0.f;
#pragma unroll
        for (int h2i = 0; h2i < 2; ++h2i) {
            const int e = sub + h2i * 16;
            float a = B1f[x * 32 + e];
#pragma unroll
            for (int i = 0; i < 8; ++i) a += qniL[x * 8 + i] * (float)W1bS[x * 256 + i * 32 + e];
            const float hid = a > 0.f ? a : (__expf(a) - 1.f);
            pp += hid * W2f[x * 32 + e];
            pb += T3f[x * 32 + e] * p.hw2[e];
        }
#pragma unroll
        for (int off = 1; off < 16; off <<= 1) {
            pp += __shfl_xor(pp, off, 64);
            pb += __shfl_xor(pb, off, 64);
        }
        const int bt = bt0 + x;
        if (sub == 0 && bt < ROWSG) p.out[bt] = pp + pb + p.hb2b2[0];
    }
}

extern "C" void kernel_launch(void* const* d_in, const int* in_sizes, int n_in,
                              void* d_out, int out_size, void* d_ws, size_t ws_size,
                              hipStream_t stream) {
    TP tp;
    tp.src[0]  = (const float*)d_in[3];   // enc_w1
    tp.src[1]  = (const float*)d_in[5];   // enc_w2
    tp.src[2]  = (const float*)d_in[7];   // wq
    tp.src[3]  = (const float*)d_in[9];   // wk
    tp.src[4]  = (const float*)d_in[11];  // wv
    tp.src[5]  = (const float*)d_in[13];  // wo
    tp.src[6]  = (const float*)d_in[17];  // ffn_w1
    tp.src[7]  = (const float*)d_in[19];  // ffn_w2
    tp.src[8]  = (const float*)d_in[27];  // w1a
    tp.src[9]  = (const float*)d_in[29];  // w1b
    tp.src[10] = (const float*)d_in[31];  // hb1w
    tp.src[11] = (const float*)d_in[33];  // w2a
    tp.src[12] = (const float*)d_in[35];  // w2b
    tp.src[13] = (const float*)d_in[37];  // hb2w1
    tp.src[14] = (const float*)d_in[23];  // fc2ni_w
    wtrans<<<(WS_TOTAL + 255) / 256, 256, 0, stream>>>(tp);

    MainP p;
    p.qvals = (const float*)d_in[0];
    p.states = (const float*)d_in[1];
    p.hid = (const float*)d_in[2];
    p.eb1 = (const float*)d_in[4];
    p.eb2 = (const float*)d_in[6];
    p.bq = (const float*)d_in[8];
    p.bk = (const float*)d_in[10];
    p.bv = (const float*)d_in[12];
    p.bo = (const float*)d_in[14];
    p.l1g = (const float*)d_in[15];
    p.l1b = (const float*)d_in[16];
    p.fb1 = (const float*)d_in[18];
    p.fb2 = (const float*)d_in[20];
    p.l2g = (const float*)d_in[21];
    p.l2b = (const float*)d_in[22];
    p.niw = (const float*)d_in[23];
    p.nib = (const float*)d_in[24];
    p.ng = (const float*)d_in[25];
    p.nb = (const float*)d_in[26];
    p.b1a = (const float*)d_in[28];
    p.b1b = (const float*)d_in[30];
    p.hb1b = (const float*)d_in[32];
    p.b2a = (const float*)d_in[34];
    p.b2b = (const float*)d_in[36];
    p.hb2b1 = (const float*)d_in[38];
    p.hw2 = (const float*)d_in[39];
    p.hb2b2 = (const float*)d_in[40];
    p.out = (float*)d_out;

    mixer_main<<<NBLK, 256, 0, stream>>>(p);
}

// Round 8
// 380.007 us; speedup vs baseline: 1.1962x; 1.1321x over previous
//
#include <hip/hip_runtime.h>
#include <hip/hip_bf16.h>

typedef __bf16 bf16x8 __attribute__((ext_vector_type(8)));
typedef __bf16 bf16x4 __attribute__((ext_vector_type(4)));
typedef float f32x4 __attribute__((ext_vector_type(4)));

#define ROWSG 32768          // B*T
#define RB 7                 // bt rows per block -> 63 valid + 1 pad = 64 supertile rows
#define NBLK 4682            // ceil(32768/7)
#define HPAD 72              // bf16 row stride
#define NN_OFF ((size_t)ROWSG)
#define EYE_OFF ((size_t)ROWSG + (size_t)ROWSG*64)

// weight-cache offsets (bf16 elements), all WT[n][k] row-major, stride = Kp
#define OFF_EW1   0          // 64 x 224 (K=200 zero-padded)
#define OFF_EW2   14336      // 64 x 64
#define OFF_WQ    18432
#define OFF_WK    22528
#define OFF_WV    26624
#define OFF_WO    30720
#define OFF_F1    34816
#define OFF_F2    38912
#define OFF_W1A   43008      // 64 x 128
#define OFF_W1B   51200      // 256 x 64
#define OFF_HB1W  67584      // 32 x 128
#define OFF_W2A   71680      // 64 x 128
#define OFF_W2B   79872      // 32 x 64
#define OFF_HB2W1 81920      // 32 x 128
#define OFF_NI    86016      // 8 mats x 16(e-pad) x 64 bf16 = 8192  (fc2ni transposed)
#define WS_TOTAL  94208

__device__ __align__(16) __bf16 g_ws[WS_TOTAL];

#define MFMA16(a,b,c) __builtin_amdgcn_mfma_f32_16x16x32_bf16(a,b,c,0,0,0)

// ---------------- weight transform kernel ----------------
struct TP { const float* src[15]; };

__global__ __launch_bounds__(256) void wtrans(TP tp) {
    const int gid = blockIdx.x * 256 + threadIdx.x;
    if (gid >= WS_TOTAL) return;
    if (gid >= OFF_NI) {
        // fc2ni [n][d][e] (8,64,7) -> [n][e'][d], e' padded to 16 with zeros
        const int loc = gid - OFF_NI;
        const int nmat = loc >> 10, rem = loc & 1023, e = rem >> 6, k = rem & 63;
        float v = (e < 7) ? tp.src[14][nmat * 448 + k * 7 + e] : 0.f;
        g_ws[gid] = (__bf16)v;
        return;
    }
    const int OFFS[14] = {OFF_EW1, OFF_EW2, OFF_WQ, OFF_WK, OFF_WV, OFF_WO, OFF_F1,
                          OFF_F2, OFF_W1A, OFF_W1B, OFF_HB1W, OFF_W2A, OFF_W2B, OFF_HB2W1};
    const int KPS[14]  = {224, 64, 64, 64, 64, 64, 64, 64, 128, 64, 128, 128, 64, 128};
    const int KRS[14]  = {200, 64, 64, 64, 64, 64, 64, 64, 128, 64, 128, 128, 64, 128};
    const int NS[14]   = {64, 64, 64, 64, 64, 64, 64, 64, 64, 256, 32, 64, 32, 32};
    int m = 0;
#pragma unroll
    for (int i = 1; i < 14; ++i) if (gid >= OFFS[i]) m = i;
    const int loc = gid - OFFS[m];
    const int Kp = KPS[m];
    const int n = loc / Kp;
    const int k = loc - n * Kp;
    float v = 0.f;
    if (k < KRS[m]) v = tp.src[m][(size_t)k * NS[m] + n];   // src is W[k][n]
    g_ws[gid] = (__bf16)v;
}

// ---------------- main fused kernel ----------------
struct MainP {
    const float *qvals, *states, *hid, *eb1, *eb2, *bq, *bk, *bv, *bo,
        *l1g, *l1b, *fb1, *fb2, *l2g, *l2b, *niw, *nib, *ng, *nb,
        *b1a, *b1b, *hb1b, *b2a, *b2b, *hb2b1, *hw2, *hb2b2;
    float* out;
};

// projection + bias + residual + LayerNorm over the 64-row supertile; wave w owns M-window w.
__device__ __forceinline__ void proj_ln4(const __bf16* A, const __bf16* WT,
                                         const float* bias, const float* g, const float* bb,
                                         __bf16* H, int w, int quad, int l15) {
    const int mt = w;
    f32x4 acc0 = {0,0,0,0}, acc1 = {0,0,0,0}, acc2 = {0,0,0,0}, acc3 = {0,0,0,0};
#pragma unroll
    for (int ks = 0; ks < 2; ++ks) {
        const int kk = ks * 32 + quad * 8;
        const bf16x8 af = *(const bf16x8*)(A + (mt * 16 + l15) * HPAD + kk);
        acc0 = MFMA16(af, *(const bf16x8*)(WT + (size_t)(0 * 16 + l15) * 64 + kk), acc0);
        acc1 = MFMA16(af, *(const bf16x8*)(WT + (size_t)(1 * 16 + l15) * 64 + kk), acc1);
        acc2 = MFMA16(af, *(const bf16x8*)(WT + (size_t)(2 * 16 + l15) * 64 + kk), acc2);
        acc3 = MFMA16(af, *(const bf16x8*)(WT + (size_t)(3 * 16 + l15) * 64 + kk), acc3);
    }
    float v[4][4], g4[4], b4[4];
#pragma unroll
    for (int nt = 0; nt < 4; ++nt) {
        const int col = nt * 16 + l15;
        const float bo = bias[col];
        g4[nt] = g[col]; b4[nt] = bb[col];
        const f32x4 a = (nt == 0) ? acc0 : (nt == 1) ? acc1 : (nt == 2) ? acc2 : acc3;
#pragma unroll
        for (int r = 0; r < 4; ++r)
            v[nt][r] = a[r] + bo + (float)H[(mt * 16 + quad * 4 + r) * HPAD + col];
    }
#pragma unroll
    for (int r = 0; r < 4; ++r) {
        float s  = v[0][r] + v[1][r] + v[2][r] + v[3][r];
        float s2 = v[0][r]*v[0][r] + v[1][r]*v[1][r] + v[2][r]*v[2][r] + v[3][r]*v[3][r];
#pragma unroll
        for (int off = 1; off < 16; off <<= 1) {
            s  += __shfl_xor(s,  off, 64);
            s2 += __shfl_xor(s2, off, 64);
        }
        const float mu  = s * 0.015625f;
        const float var = s2 * 0.015625f - mu * mu;
        const float rs  = rsqrtf(var + 1e-5f);
#pragma unroll
        for (int nt = 0; nt < 4; ++nt)
            H[(mt * 16 + quad * 4 + r) * HPAD + nt * 16 + l15] =
                (__bf16)((v[nt][r] - mu) * rs * g4[nt] + b4[nt]);
    }
}

// R4 structure (proven best: distributed jobs + 13 barriers + VGPR<=64) at RB=7:
// supertile = 63 valid rows + 1 pad (98.4% packing vs RB=6's 84%) -> 14% fewer blocks.
__global__ __launch_bounds__(256) void mixer_main(MainP p) {
    __shared__ __align__(16) __bf16 Hb[64 * HPAD];   // h -> h2 -> h3              (9216 B)
    __shared__ __align__(16) __bf16 Qb[64 * HPAD];   // Sb | q/attv | tail scratch (9216 B)
    __shared__ __align__(16) __bf16 Kb[64 * HPAD];   // k -> ah -> ffn hid | ensB  (9216 B)
    __shared__ __align__(16) __bf16 EbU[16 * HPAD];  // e | encS(rows 8..14) | Tb1 (2304 B)
    __shared__ float  attU[7 * 81];                  // att probs -> Nf            (2268 B)
    __shared__ float  sQv[56];
    __shared__ float  qniL[56];
    // total 32668 B -> 5 blocks/CU (granule-rounded 32768)

    // aliases into Qb (disjoint lifetimes; byte offsets)
    __bf16* Sb   = Qb;                       // 7x224 bf16 = 3136B      [P0..P1]
    __bf16* W1bS = Qb;                       // 7x256 bf16 = 3584B      [P10s2..P11]
    float*  B1f  = (float*)(Qb + 1792);      // @3584B..4480B, 7x32 f32
    float*  W2f  = (float*)(Qb + 2240);      // @4480B..5376B
    float*  T3f  = (float*)(Qb + 2688);      // @5376B..6272B
    __bf16* Tb2  = Qb + 3136;                // @6272B..8576B, 16x72    [P10s1..P10s2]
    float*  sNiP = (float*)(Qb + 3136);      // @6272B..7840B, 392 f32  [P9..P9b] (shares
                                             //  Tb2's slot; barrier-separated lifetimes)
    __bf16* ensB = Kb;                       // 7x136 bf16 = 1904B      [P8b..P10s2]

    const int blk = blockIdx.x;
    const int bt0 = blk * RB;
    const int t = threadIdx.x;
    const int w = t >> 6, lane = t & 63, quad = lane >> 4, l15 = lane & 15;
    const __bf16* ws = g_ws;

    // ---- P0: stage hidden_state -> Hb; states -> Sb; qvals -> sQv ----
#pragma unroll
    for (int it = 0; it < 4; ++it) {
        const int u = it * 256 + t;               // 896 float4 units = 7 rows x 512 floats
        if (u < 896) {
            const int x = u >> 7, rem = u & 127, n = rem >> 4, d4 = (rem & 15) * 4;
            const int bt = bt0 + x;
            const size_t btc = (bt < ROWSG) ? bt : (ROWSG - 1);
            const float4 v4 = *(const float4*)(p.hid + (btc * 512 + n * 64 + d4));
            bf16x4 o; o[0] = (__bf16)v4.x; o[1] = (__bf16)v4.y; o[2] = (__bf16)v4.z; o[3] = (__bf16)v4.w;
            *(bf16x4*)(Hb + (x * 9 + n) * HPAD + d4) = o;
        }
    }
#pragma unroll
    for (int it = 0; it < 2; ++it) {
        const int u = it * 256 + t;               // 350 float4 units = 7 rows x 200 floats
        if (u < 350) {
            const int xr = u / 50, c4 = u - xr * 50;
            const int bt = bt0 + xr;
            const size_t btc = (bt < ROWSG) ? bt : (ROWSG - 1);
            const float4 v4 = *(const float4*)(p.states + btc * 200 + c4 * 4);
            bf16x4 o; o[0] = (__bf16)v4.x; o[1] = (__bf16)v4.y; o[2] = (__bf16)v4.z; o[3] = (__bf16)v4.w;
            *(bf16x4*)(Sb + xr * 224 + c4 * 4) = o;
        }
    }
    if (t < 168) { const int xr = t / 24, c = t - xr * 24; Sb[xr * 224 + 200 + c] = (__bf16)0.0f; }
    if (t < 56) {
        const int bt = bt0 + (t >> 3);
        const size_t btc = (bt < ROWSG) ? bt : (ROWSG - 1);
        sQv[t] = p.qvals[btc * 8 + (t & 7)];
    }
    __syncthreads();

    // ---- P1: e = relu(S @ EW1 + eb1); row clamp for garbage A rows ----
    float e4[4];
    {
        const int n0 = w * 16;
        const int srow = (l15 < RB) ? l15 : (RB - 1);
        f32x4 acc = {0, 0, 0, 0};
        for (int ks = 0; ks < 7; ++ks) {
            const int kk = ks * 32 + quad * 8;
            const bf16x8 af = *(const bf16x8*)(Sb + srow * 224 + kk);
            const bf16x8 bf = *(const bf16x8*)(ws + OFF_EW1 + (size_t)(n0 + l15) * 224 + kk);
            acc = MFMA16(af, bf, acc);
        }
        const float b1 = p.eb1[n0 + l15];
#pragma unroll
        for (int r = 0; r < 4; ++r) {
            const float ev = fmaxf(acc[r] + b1, 0.f);
            e4[r] = ev;
            EbU[(quad * 4 + r) * HPAD + n0 + l15] = (__bf16)ev;  // all 16 rows (garbage ok)
        }
    }
    __syncthreads();

    // ---- P2: enc = tanh(e@EW2 + e + eb2) -> Hb row x*9+8, encS (EbU rows 8+x) ----
    // encS writes race with this phase's A reads of rows 8..14, but those A rows feed
    // C rows 8..14 which are discarded by the xr<RB guard (C row i depends only on A row i).
    {
        const int n0 = w * 16;
        f32x4 acc = {0, 0, 0, 0};
#pragma unroll
        for (int ks = 0; ks < 2; ++ks) {
            const int kk = ks * 32 + quad * 8;
            const bf16x8 af = *(const bf16x8*)(EbU + l15 * HPAD + kk);
            const bf16x8 bf = *(const bf16x8*)(ws + OFF_EW2 + (size_t)(n0 + l15) * 64 + kk);
            acc = MFMA16(af, bf, acc);
        }
        const float b2 = p.eb2[n0 + l15];
#pragma unroll
        for (int r = 0; r < 4; ++r) {
            const int xr = quad * 4 + r;
            if (xr < RB) {
                const float ev = tanhf(acc[r] + e4[r] + b2);
                Hb[(xr * 9 + 8) * HPAD + n0 + l15] = (__bf16)ev;
                EbU[(8 + xr) * HPAD + n0 + l15] = (__bf16)ev;   // encS, read at P8b
            }
        }
    }
    __syncthreads();

    // ---- P3: Q,K projections (32 tile-jobs, 8 per wave — distributed for ILP) ----
    for (int it = 0; it < 8; ++it) {
        const int j = w + 4 * it;                 // 0..31
        const int mat = j >> 4, r16 = j & 15, mt = r16 >> 2, nt = r16 & 3;
        const __bf16* wt = ws + (mat == 0 ? OFF_WQ : OFF_WK);
        const float* bias = (mat == 0 ? p.bq : p.bk);
        __bf16* dst = (mat == 0 ? Qb : Kb);
        f32x4 acc = {0, 0, 0, 0};
#pragma unroll
        for (int ks = 0; ks < 2; ++ks) {
            const int kk = ks * 32 + quad * 8;
            const bf16x8 af = *(const bf16x8*)(Hb + (mt * 16 + l15) * HPAD + kk);
            const bf16x8 bf = *(const bf16x8*)(wt + (size_t)(nt * 16 + l15) * 64 + kk);
            acc = MFMA16(af, bf, acc);
        }
        const float bv = bias[nt * 16 + l15];
#pragma unroll
        for (int r = 0; r < 4; ++r)
            dst[(mt * 16 + quad * 4 + r) * HPAD + nt * 16 + l15] = (__bf16)(acc[r] + bv);
    }
    __syncthreads();

    // ---- P4+P5 merged (group-local): softmax -> attP, ah = att @ h -> Kb ----
    for (int xi = 0; xi < 2; ++xi) {
        const int x = w * 2 + xi;
        if (x >= RB) continue;
        {
            // row clamp keeps reads inside the 64-row buffers for x=6 (rows would
            // otherwise run to 69); clamped B rows feed masked C cols only.
            const int arow = (x * 9 + ((l15 < 9) ? l15 : 8)) * HPAD;
            f32x4 acc = {0, 0, 0, 0};
#pragma unroll
            for (int ks = 0; ks < 2; ++ks) {
                const int kk = ks * 32 + quad * 8;
                const bf16x8 qa = *(const bf16x8*)(Qb + arow + kk);
                const bf16x8 kb = *(const bf16x8*)(Kb + arow + kk);
                acc = MFMA16(qa, kb, acc);
            }
#pragma unroll
            for (int r = 0; r < 4; ++r) {
                const int i = quad * 4 + r;
                float s = (l15 < 9) ? acc[r] * 0.125f : -3.0e38f;
                float m = s;
#pragma unroll
                for (int off = 1; off < 16; off <<= 1) m = fmaxf(m, __shfl_xor(m, off, 64));
                float e = (l15 < 9) ? __expf(s - m) : 0.f;
                float sum = e;
#pragma unroll
                for (int off = 1; off < 16; off <<= 1) sum += __shfl_xor(sum, off, 64);
                const float pv = e / sum;
                if (i < 9 && l15 < 9) attU[x * 81 + i * 9 + l15] = pv;
            }
        }
        // ah (this wave wrote this group's attP; K rows of this group now dead)
        {
            float vreg[9];
#pragma unroll
            for (int jj = 0; jj < 9; ++jj) vreg[jj] = (float)Hb[(x * 9 + jj) * HPAD + lane];
#pragma unroll
            for (int i = 0; i < 9; ++i) {
                float a = 0.f;
#pragma unroll
                for (int jj = 0; jj < 9; ++jj) a += attU[x * 81 + i * 9 + jj] * vreg[jj];
                Kb[(x * 9 + i) * HPAD + lane] = (__bf16)a;
            }
        }
    }
    __syncthreads();

    // ---- P6a: attv = ah @ wv + bv -> Qb (16 jobs, 4 per wave) ----
    for (int it = 0; it < 4; ++it) {
        const int j = w + 4 * it;
        const int mt = j >> 2, nt = j & 3;
        f32x4 acc = {0, 0, 0, 0};
#pragma unroll
        for (int ks = 0; ks < 2; ++ks) {
            const int kk = ks * 32 + quad * 8;
            const bf16x8 af = *(const bf16x8*)(Kb + (mt * 16 + l15) * HPAD + kk);
            const bf16x8 bf = *(const bf16x8*)(ws + OFF_WV + (size_t)(nt * 16 + l15) * 64 + kk);
            acc = MFMA16(af, bf, acc);
        }
        const float bv = p.bv[nt * 16 + l15];
#pragma unroll
        for (int r = 0; r < 4; ++r)
            Qb[(mt * 16 + quad * 4 + r) * HPAD + nt * 16 + l15] = (__bf16)(acc[r] + bv);
    }
    __syncthreads();

    // ---- P6b: o-proj + residual(h) + LN1 -> h2 in Hb ----
    proj_ln4(Qb, ws + OFF_WO, p.bo, p.l1g, p.l1b, Hb, w, quad, l15);
    __syncthreads();

    // ---- P7: FFN1: f = relu(h2@W1 + b1) -> Kb (16 jobs) ----
    for (int it = 0; it < 4; ++it) {
        const int j = w + 4 * it;
        const int mt = j >> 2, nt = j & 3;
        f32x4 acc = {0, 0, 0, 0};
#pragma unroll
        for (int ks = 0; ks < 2; ++ks) {
            const int kk = ks * 32 + quad * 8;
            const bf16x8 af = *(const bf16x8*)(Hb + (mt * 16 + l15) * HPAD + kk);
            const bf16x8 bf = *(const bf16x8*)(ws + OFF_F1 + (size_t)(nt * 16 + l15) * 64 + kk);
            acc = MFMA16(af, bf, acc);
        }
        const float fb = p.fb1[nt * 16 + l15];
#pragma unroll
        for (int r = 0; r < 4; ++r)
            Kb[(mt * 16 + quad * 4 + r) * HPAD + nt * 16 + l15] = (__bf16)fmaxf(acc[r] + fb, 0.f);
    }
    __syncthreads();

    // ---- P8: FFN2 + residual(h2) + LN2 -> h3 in Hb ----
    proj_ln4(Kb, ws + OFF_F2, p.fb2, p.l2g, p.l2b, Hb, w, quad, l15);
    __syncthreads();

    // ---- P8b + P9 merged (both read-only on Hb) ----
    // P8b: ensB = [enc (from encS) | mean over 8 heads of h3] -> Kb
    {
#pragma unroll
        for (int it = 0; it < 2; ++it) {
            const int u = it * 256 + t;
            if (u < RB * 64) {
                const int x = u >> 6, col = u & 63;
                float s = 0.f;
#pragma unroll
                for (int i = 0; i < 8; ++i) s += (float)Hb[(x * 9 + i) * HPAD + col];
                ensB[x * 136 + 64 + col] = (__bf16)(s * 0.125f);
                ensB[x * 136 + col] = EbU[(8 + x) * HPAD + col];
            }
        }
    }
    // P9: ni = sigmoid(LN7(h3[:, :8]@fc2ni + nib)) via MFMA (2 jobs/wave)
    for (int jn = 0; jn < 2; ++jn) {
        const int n = w * 2 + jn;
        const int l15c = (l15 < RB) ? l15 : (RB - 1);   // clamp garbage A rows in-bounds
        f32x4 acc = {0, 0, 0, 0};
#pragma unroll
        for (int ks = 0; ks < 2; ++ks) {
            const int kk = ks * 32 + quad * 8;
            const bf16x8 af = *(const bf16x8*)(Hb + (l15c * 9 + n) * HPAD + kk);
            const bf16x8 bf = *(const bf16x8*)(ws + OFF_NI + n * 1024 + (size_t)l15 * 64 + kk);
            acc = MFMA16(af, bf, acc);
        }
#pragma unroll
        for (int r = 0; r < 4; ++r) {
            const int x = quad * 4 + r;
            const float av = (l15 < 7) ? (acc[r] + p.nib[n * 7 + l15]) : 0.f;
            float s1 = av;
            s1 += __shfl_xor(s1, 1, 64); s1 += __shfl_xor(s1, 2, 64);
            s1 += __shfl_xor(s1, 4, 64); s1 += __shfl_xor(s1, 8, 64);
            const float mu = s1 * (1.f / 7.f);
            float d0 = (l15 < 7) ? (av - mu) : 0.f;
            float s2 = d0 * d0;
            s2 += __shfl_xor(s2, 1, 64); s2 += __shfl_xor(s2, 2, 64);
            s2 += __shfl_xor(s2, 4, 64); s2 += __shfl_xor(s2, 8, 64);
            const float rs = rsqrtf(s2 * (1.f / 7.f) + 1e-5f);
            if (x < RB && l15 < 7) {
                const float vv = (av - mu) * rs * p.ng[l15] + p.nb[l15];
                sNiP[(x * 8 + n) * 7 + l15] = 1.f / (1.f + __expf(-vv));
            }
        }
    }
    __syncthreads();

    // ---- P9b: N_nn + eye_mask outputs, Nf -> attU ----
    {
        float* Nf = attU;
#pragma unroll
        for (int it = 0; it < 2; ++it) {
            const int u = it * 256 + t;
            if (u < RB * 64) {
                const int x = u >> 6, rem = u & 63, i = rem >> 3, jj = rem & 7;
                const float nf = (i == jj) ? 1.f : sNiP[(x * 8 + i) * 7 + jj - (jj > i ? 1 : 0)];
                const int bt = bt0 + x;
                if (bt < ROWSG) {
                    p.out[NN_OFF + (size_t)bt * 64 + rem] = nf;
                    p.out[EYE_OFF + (size_t)bt * 64 + rem] = (i == jj) ? 1.f : 0.f;
                }
                Nf[x * 64 + rem] = nf;
            }
        }
    }
    __syncthreads();

    // ---- merged: q_ni (reads Nf,sQv) + P10s1 (reads ensB) — disjoint LDS ----
    if (t < RB * 32) {
        const float* Nf = attU;
        const int pr = t >> 2, q4 = t & 3;
        const int x = pr >> 3, i = pr & 7;
        const int j0 = q4 * 2;
        float s = sQv[x * 8 + j0] * Nf[x * 64 + i * 8 + j0] +
                  sQv[x * 8 + j0 + 1] * Nf[x * 64 + i * 8 + j0 + 1];
        s += __shfl_xor(s, 1, 64);
        s += __shfl_xor(s, 2, 64);
        if (q4 == 0) qniL[x * 8 + i] = s;
    }
    // P10s1: t1 = relu(ens@w1a+b1a) -> Tb1(EbU); t2 = relu(ens@w2a+b2a) -> Tb2
    {
        const int n0 = w * 16;
#pragma unroll
        for (int m2 = 0; m2 < 2; ++m2) {
            const __bf16* wt = ws + (m2 == 0 ? OFF_W1A : OFF_W2A);
            const float* bias = m2 == 0 ? p.b1a : p.b2a;
            __bf16* dst = m2 == 0 ? EbU : Tb2;
            f32x4 acc = {0, 0, 0, 0};
#pragma unroll
            for (int ks = 0; ks < 4; ++ks) {
                const int kk = ks * 32 + quad * 8;
                const bf16x8 af = *(const bf16x8*)(ensB + l15 * 136 + kk);
                const bf16x8 bf = *(const bf16x8*)(wt + (size_t)(n0 + l15) * 128 + kk);
                acc = MFMA16(af, bf, acc);
            }
            const float bb = bias[n0 + l15];
#pragma unroll
            for (int r = 0; r < 4; ++r)
                dst[(quad * 4 + r) * HPAD + n0 + l15] = (__bf16)fmaxf(acc[r] + bb, 0.f);
        }
    }
    __syncthreads();

    // ---- P10s2: w1 (16 jobs), b1 (2), w2 (2), t3 (2) = 22 tile-jobs ----
    for (int it = 0; it < 6; ++it) {
        const int j = w + 4 * it;
        if (j >= 22) continue;
        int mode, n0, Kp, ksteps, aStride;
        const __bf16 *A, *WT; const float* bias;
        if (j < 16)      { mode = 0; n0 = j * 16;        A = EbU;  aStride = HPAD; WT = ws + OFF_W1B;   bias = p.b1b;  Kp = 64;  ksteps = 2; }
        else if (j < 18) { mode = 1; n0 = (j - 16) * 16; A = ensB; aStride = 136;  WT = ws + OFF_HB1W;  bias = p.hb1b; Kp = 128; ksteps = 4; }
        else if (j < 20) { mode = 2; n0 = (j - 18) * 16; A = Tb2;  aStride = HPAD; WT = ws + OFF_W2B;   bias = p.b2b;  Kp = 64;  ksteps = 2; }
        else             { mode = 3; n0 = (j - 20) * 16; A = ensB; aStride = 136;  WT = ws + OFF_HB2W1; bias = p.hb2b1;Kp = 128; ksteps = 4; }
        f32x4 acc = {0, 0, 0, 0};
        for (int ks = 0; ks < ksteps; ++ks) {
            const int kk = ks * 32 + quad * 8;
            const bf16x8 af = *(const bf16x8*)(A + l15 * aStride + kk);
            const bf16x8 bf = *(const bf16x8*)(WT + (size_t)(n0 + l15) * Kp + kk);
            acc = MFMA16(af, bf, acc);
        }
        const float bb = bias[n0 + l15];
#pragma unroll
        for (int r = 0; r < 4; ++r) {
            const int xr = quad * 4 + r;
            if (xr < RB) {
                const float val = acc[r] + bb;
                if (mode == 0)      W1bS[xr * 256 + n0 + l15] = (__bf16)fabsf(val);
                else if (mode == 1) B1f[xr * 32 + n0 + l15] = val;
                else if (mode == 2) W2f[xr * 32 + n0 + l15] = fabsf(val);
                else                T3f[xr * 32 + n0 + l15] = fmaxf(val, 0.f);
            }
        }
    }
    __syncthreads();

    // ---- P11: hidden = elu(q_ni@w1 + b1); y = hidden@w2 + t3@hw2 + hb2b2 ----
    if (t < RB * 16) {
        const int x = t >> 4, sub = t & 15;
        float pp = 0.f, pb = 0.f;
#pragma unroll
        for (int h2i = 0; h2i < 2; ++h2i) {
            const int e = sub + h2i * 16;
            float a = B1f[x * 32 + e];
#pragma unroll
            for (int i = 0; i < 8; ++i) a += qniL[x * 8 + i] * (float)W1bS[x * 256 + i * 32 + e];
            const float hid = a > 0.f ? a : (__expf(a) - 1.f);
            pp += hid * W2f[x * 32 + e];
            pb += T3f[x * 32 + e] * p.hw2[e];
        }
#pragma unroll
        for (int off = 1; off < 16; off <<= 1) {
            pp += __shfl_xor(pp, off, 64);
            pb += __shfl_xor(pb, off, 64);
        }
        const int bt = bt0 + x;
        if (sub == 0 && bt < ROWSG) p.out[bt] = pp + pb + p.hb2b2[0];
    }
}

extern "C" void kernel_launch(void* const* d_in, const int* in_sizes, int n_in,
                              void* d_out, int out_size, void* d_ws, size_t ws_size,
                              hipStream_t stream) {
    TP tp;
    tp.src[0]  = (const float*)d_in[3];   // enc_w1
    tp.src[1]  = (const float*)d_in[5];   // enc_w2
    tp.src[2]  = (const float*)d_in[7];   // wq
    tp.src[3]  = (const float*)d_in[9];   // wk
    tp.src[4]  = (const float*)d_in[11];  // wv
    tp.src[5]  = (const float*)d_in[13];  // wo
    tp.src[6]  = (const float*)d_in[17];  // ffn_w1
    tp.src[7]  = (const float*)d_in[19];  // ffn_w2
    tp.src[8]  = (const float*)d_in[27];  // w1a
    tp.src[9]  = (const float*)d_in[29];  // w1b
    tp.src[10] = (const float*)d_in[31];  // hb1w
    tp.src[11] = (const float*)d_in[33];  // w2a
    tp.src[12] = (const float*)d_in[35];  // w2b
    tp.src[13] = (const float*)d_in[37];  // hb2w1
    tp.src[14] = (const float*)d_in[23];  // fc2ni_w
    wtrans<<<(WS_TOTAL + 255) / 256, 256, 0, stream>>>(tp);

    MainP p;
    p.qvals = (const float*)d_in[0];
    p.states = (const float*)d_in[1];
    p.hid = (const float*)d_in[2];
    p.eb1 = (const float*)d_in[4];
    p.eb2 = (const float*)d_in[6];
    p.bq = (const float*)d_in[8];
    p.bk = (const float*)d_in[10];
    p.bv = (const float*)d_in[12];
    p.bo = (const float*)d_in[14];
    p.l1g = (const float*)d_in[15];
    p.l1b = (const float*)d_in[16];
    p.fb1 = (const float*)d_in[18];
    p.fb2 = (const float*)d_in[20];
    p.l2g = (const float*)d_in[21];
    p.l2b = (const float*)d_in[22];
    p.niw = (const float*)d_in[23];
    p.nib = (const float*)d_in[24];
    p.ng = (const float*)d_in[25];
    p.nb = (const float*)d_in[26];
    p.b1a = (const float*)d_in[28];
    p.b1b = (const float*)d_in[30];
    p.hb1b = (const float*)d_in[32];
    p.b2a = (const float*)d_in[34];
    p.b2b = (const float*)d_in[36];
    p.hb2b1 = (const float*)d_in[38];
    p.hw2 = (const float*)d_in[39];
    p.hb2b2 = (const float*)d_in[40];
    p.out = (float*)d_out;

    mixer_main<<<NBLK, 256, 0, stream>>>(p);
}

// Round 9
// 379.498 us; speedup vs baseline: 1.1978x; 1.0013x over previous
//
#include <hip/hip_runtime.h>
#include <hip/hip_bf16.h>

typedef __bf16 bf16x8 __attribute__((ext_vector_type(8)));
typedef __bf16 bf16x4 __attribute__((ext_vector_type(4)));
typedef float f32x4 __attribute__((ext_vector_type(4)));

#define ROWSG 32768          // B*T
#define RB 7                 // bt rows per block -> 63 valid + 1 pad = 64 supertile rows
#define NBLK 4682            // ceil(32768/7)
#define HPAD 72              // bf16 row stride
#define NN_OFF ((size_t)ROWSG)
#define EYE_OFF ((size_t)ROWSG + (size_t)ROWSG*64)

// weight-cache offsets (bf16 elements), all WT[n][k] row-major, stride = Kp
#define OFF_EW1   0          // 64 x 224 (K=200 zero-padded)
#define OFF_EW2   14336      // 64 x 64
#define OFF_WQ    18432
#define OFF_WK    22528
#define OFF_WV    26624
#define OFF_WO    30720
#define OFF_F1    34816
#define OFF_F2    38912
#define OFF_W1A   43008      // 64 x 128
#define OFF_W1B   51200      // 256 x 64
#define OFF_HB1W  67584      // 32 x 128
#define OFF_W2A   71680      // 64 x 128
#define OFF_W2B   79872      // 32 x 64
#define OFF_HB2W1 81920      // 32 x 128
#define OFF_NI    86016      // 8 mats x 16(e-pad) x 64 bf16 = 8192  (fc2ni transposed)
#define WS_TOTAL  94208

__device__ __align__(16) __bf16 g_ws[WS_TOTAL];

#define MFMA16(a,b,c) __builtin_amdgcn_mfma_f32_16x16x32_bf16(a,b,c,0,0,0)

// ---------------- weight transform kernel ----------------
struct TP { const float* src[15]; };

__global__ __launch_bounds__(256) void wtrans(TP tp) {
    const int gid = blockIdx.x * 256 + threadIdx.x;
    if (gid >= WS_TOTAL) return;
    if (gid >= OFF_NI) {
        // fc2ni [n][d][e] (8,64,7) -> [n][e'][d], e' padded to 16 with zeros
        const int loc = gid - OFF_NI;
        const int nmat = loc >> 10, rem = loc & 1023, e = rem >> 6, k = rem & 63;
        float v = (e < 7) ? tp.src[14][nmat * 448 + k * 7 + e] : 0.f;
        g_ws[gid] = (__bf16)v;
        return;
    }
    const int OFFS[14] = {OFF_EW1, OFF_EW2, OFF_WQ, OFF_WK, OFF_WV, OFF_WO, OFF_F1,
                          OFF_F2, OFF_W1A, OFF_W1B, OFF_HB1W, OFF_W2A, OFF_W2B, OFF_HB2W1};
    const int KPS[14]  = {224, 64, 64, 64, 64, 64, 64, 64, 128, 64, 128, 128, 64, 128};
    const int KRS[14]  = {200, 64, 64, 64, 64, 64, 64, 64, 128, 64, 128, 128, 64, 128};
    const int NS[14]   = {64, 64, 64, 64, 64, 64, 64, 64, 64, 256, 32, 64, 32, 32};
    int m = 0;
#pragma unroll
    for (int i = 1; i < 14; ++i) if (gid >= OFFS[i]) m = i;
    const int loc = gid - OFFS[m];
    const int Kp = KPS[m];
    const int n = loc / Kp;
    const int k = loc - n * Kp;
    float v = 0.f;
    if (k < KRS[m]) v = tp.src[m][(size_t)k * NS[m] + n];   // src is W[k][n]
    g_ws[gid] = (__bf16)v;
}

// ---------------- main fused kernel ----------------
struct MainP {
    const float *qvals, *states, *hid, *eb1, *eb2, *bq, *bk, *bv, *bo,
        *l1g, *l1b, *fb1, *fb2, *l2g, *l2b, *niw, *nib, *ng, *nb,
        *b1a, *b1b, *hb1b, *b2a, *b2b, *hb2b1, *hw2, *hb2b2;
    float* out;
};

// projection + bias + residual + LayerNorm over the 64-row supertile; wave w owns M-window w.
__device__ __forceinline__ void proj_ln4(const __bf16* A, const __bf16* WT,
                                         const float* bias, const float* g, const float* bb,
                                         __bf16* H, int w, int quad, int l15) {
    const int mt = w;
    f32x4 acc0 = {0,0,0,0}, acc1 = {0,0,0,0}, acc2 = {0,0,0,0}, acc3 = {0,0,0,0};
#pragma unroll
    for (int ks = 0; ks < 2; ++ks) {
        const int kk = ks * 32 + quad * 8;
        const bf16x8 af = *(const bf16x8*)(A + (mt * 16 + l15) * HPAD + kk);
        acc0 = MFMA16(af, *(const bf16x8*)(WT + (size_t)(0 * 16 + l15) * 64 + kk), acc0);
        acc1 = MFMA16(af, *(const bf16x8*)(WT + (size_t)(1 * 16 + l15) * 64 + kk), acc1);
        acc2 = MFMA16(af, *(const bf16x8*)(WT + (size_t)(2 * 16 + l15) * 64 + kk), acc2);
        acc3 = MFMA16(af, *(const bf16x8*)(WT + (size_t)(3 * 16 + l15) * 64 + kk), acc3);
    }
    float v[4][4], g4[4], b4[4];
#pragma unroll
    for (int nt = 0; nt < 4; ++nt) {
        const int col = nt * 16 + l15;
        const float bo = bias[col];
        g4[nt] = g[col]; b4[nt] = bb[col];
        const f32x4 a = (nt == 0) ? acc0 : (nt == 1) ? acc1 : (nt == 2) ? acc2 : acc3;
#pragma unroll
        for (int r = 0; r < 4; ++r)
            v[nt][r] = a[r] + bo + (float)H[(mt * 16 + quad * 4 + r) * HPAD + col];
    }
#pragma unroll
    for (int r = 0; r < 4; ++r) {
        float s  = v[0][r] + v[1][r] + v[2][r] + v[3][r];
        float s2 = v[0][r]*v[0][r] + v[1][r]*v[1][r] + v[2][r]*v[2][r] + v[3][r]*v[3][r];
#pragma unroll
        for (int off = 1; off < 16; off <<= 1) {
            s  += __shfl_xor(s,  off, 64);
            s2 += __shfl_xor(s2, off, 64);
        }
        const float mu  = s * 0.015625f;
        const float var = s2 * 0.015625f - mu * mu;
        const float rs  = rsqrtf(var + 1e-5f);
#pragma unroll
        for (int nt = 0; nt < 4; ++nt)
            H[(mt * 16 + quad * 4 + r) * HPAD + nt * 16 + l15] =
                (__bf16)((v[nt][r] - mu) * rs * g4[nt] + b4[nt]);
    }
}

// R8 structure (proven best: RB=7, distributed jobs, 13 barriers, VGPR<=64, 5 blocks/CU)
// + scalar-tail cuts: attP 10-float rows w/ float2 reads; float4 output stores;
// sQv dropped (qvals re-read at q_ni) to pay for attU growth.
__global__ __launch_bounds__(256) void mixer_main(MainP p) {
    __shared__ __align__(16) __bf16 Hb[64 * HPAD];   // h -> h2 -> h3              (9216 B)
    __shared__ __align__(16) __bf16 Qb[64 * HPAD];   // Sb | q/attv | tail scratch (9216 B)
    __shared__ __align__(16) __bf16 Kb[64 * HPAD];   // k -> ah -> ffn hid | ensB  (9216 B)
    __shared__ __align__(16) __bf16 EbU[16 * HPAD];  // e | encS(rows 8..14) | Tb1 (2304 B)
    __shared__ __align__(16) float  attU[7 * 90];    // att probs (10-f rows) -> Nf (2520 B)
    __shared__ float  qniL[56];                      //                            (224 B)
    // total 32696 B -> 5 blocks/CU (granule 32768)

    // aliases into Qb (disjoint lifetimes; byte offsets)
    __bf16* Sb   = Qb;                       // 7x224 bf16 = 3136B      [P0..P1]
    __bf16* W1bS = Qb;                       // 7x256 bf16 = 3584B      [P10s2..P11]
    float*  B1f  = (float*)(Qb + 1792);      // @3584B..4480B, 7x32 f32
    float*  W2f  = (float*)(Qb + 2240);      // @4480B..5376B
    float*  T3f  = (float*)(Qb + 2688);      // @5376B..6272B
    __bf16* Tb2  = Qb + 3136;                // @6272B..8576B, 16x72    [P10s1..P10s2]
    float*  sNiP = (float*)(Qb + 3136);      // @6272B..7840B, 392 f32  [P9..P9b] (shares
                                             //  Tb2's slot; barrier-separated lifetimes)
    __bf16* ensB = Kb;                       // 7x136 bf16 = 1904B      [P8b..P10s2]

    const int blk = blockIdx.x;
    const int bt0 = blk * RB;
    const int t = threadIdx.x;
    const int w = t >> 6, lane = t & 63, quad = lane >> 4, l15 = lane & 15;
    const __bf16* ws = g_ws;

    // ---- P0: stage hidden_state -> Hb; states -> Sb ----
#pragma unroll
    for (int it = 0; it < 4; ++it) {
        const int u = it * 256 + t;               // 896 float4 units = 7 rows x 512 floats
        if (u < 896) {
            const int x = u >> 7, rem = u & 127, n = rem >> 4, d4 = (rem & 15) * 4;
            const int bt = bt0 + x;
            const size_t btc = (bt < ROWSG) ? bt : (ROWSG - 1);
            const float4 v4 = *(const float4*)(p.hid + (btc * 512 + n * 64 + d4));
            bf16x4 o; o[0] = (__bf16)v4.x; o[1] = (__bf16)v4.y; o[2] = (__bf16)v4.z; o[3] = (__bf16)v4.w;
            *(bf16x4*)(Hb + (x * 9 + n) * HPAD + d4) = o;
        }
    }
#pragma unroll
    for (int it = 0; it < 2; ++it) {
        const int u = it * 256 + t;               // 350 float4 units = 7 rows x 200 floats
        if (u < 350) {
            const int xr = u / 50, c4 = u - xr * 50;
            const int bt = bt0 + xr;
            const size_t btc = (bt < ROWSG) ? bt : (ROWSG - 1);
            const float4 v4 = *(const float4*)(p.states + btc * 200 + c4 * 4);
            bf16x4 o; o[0] = (__bf16)v4.x; o[1] = (__bf16)v4.y; o[2] = (__bf16)v4.z; o[3] = (__bf16)v4.w;
            *(bf16x4*)(Sb + xr * 224 + c4 * 4) = o;
        }
    }
    if (t < 168) { const int xr = t / 24, c = t - xr * 24; Sb[xr * 224 + 200 + c] = (__bf16)0.0f; }
    __syncthreads();

    // ---- P1: e = relu(S @ EW1 + eb1); row clamp for garbage A rows ----
    float e4[4];
    {
        const int n0 = w * 16;
        const int srow = (l15 < RB) ? l15 : (RB - 1);
        f32x4 acc = {0, 0, 0, 0};
        for (int ks = 0; ks < 7; ++ks) {
            const int kk = ks * 32 + quad * 8;
            const bf16x8 af = *(const bf16x8*)(Sb + srow * 224 + kk);
            const bf16x8 bf = *(const bf16x8*)(ws + OFF_EW1 + (size_t)(n0 + l15) * 224 + kk);
            acc = MFMA16(af, bf, acc);
        }
        const float b1 = p.eb1[n0 + l15];
#pragma unroll
        for (int r = 0; r < 4; ++r) {
            const float ev = fmaxf(acc[r] + b1, 0.f);
            e4[r] = ev;
            EbU[(quad * 4 + r) * HPAD + n0 + l15] = (__bf16)ev;  // all 16 rows (garbage ok)
        }
    }
    __syncthreads();

    // ---- P2: enc = tanh(e@EW2 + e + eb2) -> Hb row x*9+8, encS (EbU rows 8+x) ----
    // encS writes race with this phase's A reads of rows 8..14, but those A rows feed
    // C rows 8..14 which are discarded by the xr<RB guard (C row i depends only on A row i).
    {
        const int n0 = w * 16;
        f32x4 acc = {0, 0, 0, 0};
#pragma unroll
        for (int ks = 0; ks < 2; ++ks) {
            const int kk = ks * 32 + quad * 8;
            const bf16x8 af = *(const bf16x8*)(EbU + l15 * HPAD + kk);
            const bf16x8 bf = *(const bf16x8*)(ws + OFF_EW2 + (size_t)(n0 + l15) * 64 + kk);
            acc = MFMA16(af, bf, acc);
        }
        const float b2 = p.eb2[n0 + l15];
#pragma unroll
        for (int r = 0; r < 4; ++r) {
            const int xr = quad * 4 + r;
            if (xr < RB) {
                const float ev = tanhf(acc[r] + e4[r] + b2);
                Hb[(xr * 9 + 8) * HPAD + n0 + l15] = (__bf16)ev;
                EbU[(8 + xr) * HPAD + n0 + l15] = (__bf16)ev;   // encS, read at P8b
            }
        }
    }
    __syncthreads();

    // ---- P3: Q,K projections (32 tile-jobs, 8 per wave — distributed for ILP) ----
    for (int it = 0; it < 8; ++it) {
        const int j = w + 4 * it;                 // 0..31
        const int mat = j >> 4, r16 = j & 15, mt = r16 >> 2, nt = r16 & 3;
        const __bf16* wt = ws + (mat == 0 ? OFF_WQ : OFF_WK);
        const float* bias = (mat == 0 ? p.bq : p.bk);
        __bf16* dst = (mat == 0 ? Qb : Kb);
        f32x4 acc = {0, 0, 0, 0};
#pragma unroll
        for (int ks = 0; ks < 2; ++ks) {
            const int kk = ks * 32 + quad * 8;
            const bf16x8 af = *(const bf16x8*)(Hb + (mt * 16 + l15) * HPAD + kk);
            const bf16x8 bf = *(const bf16x8*)(wt + (size_t)(nt * 16 + l15) * 64 + kk);
            acc = MFMA16(af, bf, acc);
        }
        const float bv = bias[nt * 16 + l15];
#pragma unroll
        for (int r = 0; r < 4; ++r)
            dst[(mt * 16 + quad * 4 + r) * HPAD + nt * 16 + l15] = (__bf16)(acc[r] + bv);
    }
    __syncthreads();

    // ---- P4+P5 merged (group-local): softmax -> attP (10-f rows), ah = att @ h -> Kb ----
    for (int xi = 0; xi < 2; ++xi) {
        const int x = w * 2 + xi;
        if (x >= RB) continue;
        {
            // row clamp keeps reads inside the 64-row buffers for x=6 (rows would
            // otherwise run to 69); clamped B rows feed masked C cols only.
            const int arow = (x * 9 + ((l15 < 9) ? l15 : 8)) * HPAD;
            f32x4 acc = {0, 0, 0, 0};
#pragma unroll
            for (int ks = 0; ks < 2; ++ks) {
                const int kk = ks * 32 + quad * 8;
                const bf16x8 qa = *(const bf16x8*)(Qb + arow + kk);
                const bf16x8 kb = *(const bf16x8*)(Kb + arow + kk);
                acc = MFMA16(qa, kb, acc);
            }
#pragma unroll
            for (int r = 0; r < 4; ++r) {
                const int i = quad * 4 + r;
                float s = (l15 < 9) ? acc[r] * 0.125f : -3.0e38f;
                float m = s;
#pragma unroll
                for (int off = 1; off < 16; off <<= 1) m = fmaxf(m, __shfl_xor(m, off, 64));
                float e = (l15 < 9) ? __expf(s - m) : 0.f;
                float sum = e;
#pragma unroll
                for (int off = 1; off < 16; off <<= 1) sum += __shfl_xor(sum, off, 64);
                const float pv = e / sum;
                if (i < 9 && l15 < 9) attU[x * 90 + i * 10 + l15] = pv;
            }
        }
        // ah: att rows via 4x float2 + 1 scalar (wave-uniform broadcast reads)
        {
            float vreg[9];
#pragma unroll
            for (int jj = 0; jj < 9; ++jj) vreg[jj] = (float)Hb[(x * 9 + jj) * HPAD + lane];
#pragma unroll
            for (int i = 0; i < 9; ++i) {
                const float* ar = attU + x * 90 + i * 10;
                const float2 a0 = *(const float2*)(ar);
                const float2 a1 = *(const float2*)(ar + 2);
                const float2 a2 = *(const float2*)(ar + 4);
                const float2 a3 = *(const float2*)(ar + 6);
                const float a8 = ar[8];
                const float a = a0.x * vreg[0] + a0.y * vreg[1] + a1.x * vreg[2] + a1.y * vreg[3]
                              + a2.x * vreg[4] + a2.y * vreg[5] + a3.x * vreg[6] + a3.y * vreg[7]
                              + a8 * vreg[8];
                Kb[(x * 9 + i) * HPAD + lane] = (__bf16)a;
            }
        }
    }
    __syncthreads();

    // ---- P6a: attv = ah @ wv + bv -> Qb (16 jobs, 4 per wave) ----
    for (int it = 0; it < 4; ++it) {
        const int j = w + 4 * it;
        const int mt = j >> 2, nt = j & 3;
        f32x4 acc = {0, 0, 0, 0};
#pragma unroll
        for (int ks = 0; ks < 2; ++ks) {
            const int kk = ks * 32 + quad * 8;
            const bf16x8 af = *(const bf16x8*)(Kb + (mt * 16 + l15) * HPAD + kk);
            const bf16x8 bf = *(const bf16x8*)(ws + OFF_WV + (size_t)(nt * 16 + l15) * 64 + kk);
            acc = MFMA16(af, bf, acc);
        }
        const float bv = p.bv[nt * 16 + l15];
#pragma unroll
        for (int r = 0; r < 4; ++r)
            Qb[(mt * 16 + quad * 4 + r) * HPAD + nt * 16 + l15] = (__bf16)(acc[r] + bv);
    }
    __syncthreads();

    // ---- P6b: o-proj + residual(h) + LN1 -> h2 in Hb ----
    proj_ln4(Qb, ws + OFF_WO, p.bo, p.l1g, p.l1b, Hb, w, quad, l15);
    __syncthreads();

    // ---- P7: FFN1: f = relu(h2@W1 + b1) -> Kb (16 jobs) ----
    for (int it = 0; it < 4; ++it) {
        const int j = w + 4 * it;
        const int mt = j >> 2, nt = j & 3;
        f32x4 acc = {0, 0, 0, 0};
#pragma unroll
        for (int ks = 0; ks < 2; ++ks) {
            const int kk = ks * 32 + quad * 8;
            const bf16x8 af = *(const bf16x8*)(Hb + (mt * 16 + l15) * HPAD + kk);
            const bf16x8 bf = *(const bf16x8*)(ws + OFF_F1 + (size_t)(nt * 16 + l15) * 64 + kk);
            acc = MFMA16(af, bf, acc);
        }
        const float fb = p.fb1[nt * 16 + l15];
#pragma unroll
        for (int r = 0; r < 4; ++r)
            Kb[(mt * 16 + quad * 4 + r) * HPAD + nt * 16 + l15] = (__bf16)fmaxf(acc[r] + fb, 0.f);
    }
    __syncthreads();

    // ---- P8: FFN2 + residual(h2) + LN2 -> h3 in Hb ----
    proj_ln4(Kb, ws + OFF_F2, p.fb2, p.l2g, p.l2b, Hb, w, quad, l15);
    __syncthreads();

    // ---- P8b + P9 merged (both read-only on Hb) ----
    // P8b: ensB = [enc (from encS) | mean over 8 heads of h3] -> Kb
    {
#pragma unroll
        for (int it = 0; it < 2; ++it) {
            const int u = it * 256 + t;
            if (u < RB * 64) {
                const int x = u >> 6, col = u & 63;
                float s = 0.f;
#pragma unroll
                for (int i = 0; i < 8; ++i) s += (float)Hb[(x * 9 + i) * HPAD + col];
                ensB[x * 136 + 64 + col] = (__bf16)(s * 0.125f);
                ensB[x * 136 + col] = EbU[(8 + x) * HPAD + col];
            }
        }
    }
    // P9: ni = sigmoid(LN7(h3[:, :8]@fc2ni + nib)) via MFMA (2 jobs/wave)
    for (int jn = 0; jn < 2; ++jn) {
        const int n = w * 2 + jn;
        const int l15c = (l15 < RB) ? l15 : (RB - 1);   // clamp garbage A rows in-bounds
        f32x4 acc = {0, 0, 0, 0};
#pragma unroll
        for (int ks = 0; ks < 2; ++ks) {
            const int kk = ks * 32 + quad * 8;
            const bf16x8 af = *(const bf16x8*)(Hb + (l15c * 9 + n) * HPAD + kk);
            const bf16x8 bf = *(const bf16x8*)(ws + OFF_NI + n * 1024 + (size_t)l15 * 64 + kk);
            acc = MFMA16(af, bf, acc);
        }
#pragma unroll
        for (int r = 0; r < 4; ++r) {
            const int x = quad * 4 + r;
            const float av = (l15 < 7) ? (acc[r] + p.nib[n * 7 + l15]) : 0.f;
            float s1 = av;
            s1 += __shfl_xor(s1, 1, 64); s1 += __shfl_xor(s1, 2, 64);
            s1 += __shfl_xor(s1, 4, 64); s1 += __shfl_xor(s1, 8, 64);
            const float mu = s1 * (1.f / 7.f);
            float d0 = (l15 < 7) ? (av - mu) : 0.f;
            float s2 = d0 * d0;
            s2 += __shfl_xor(s2, 1, 64); s2 += __shfl_xor(s2, 2, 64);
            s2 += __shfl_xor(s2, 4, 64); s2 += __shfl_xor(s2, 8, 64);
            const float rs = rsqrtf(s2 * (1.f / 7.f) + 1e-5f);
            if (x < RB && l15 < 7) {
                const float vv = (av - mu) * rs * p.ng[l15] + p.nb[l15];
                sNiP[(x * 8 + n) * 7 + l15] = 1.f / (1.f + __expf(-vv));
            }
        }
    }
    __syncthreads();

    // ---- P9b: N_nn + eye_mask outputs via float4 (112 threads), Nf -> attU ----
    {
        float* Nf = attU;
        if (t < RB * 16) {
            const int x = t >> 4, c4 = (t & 15) * 4;    // 4 consecutive cols, same i-row
            const int i = c4 >> 3;
            float4 nv, ev;
            float* nvp = &nv.x; float* evp = &ev.x;
#pragma unroll
            for (int k = 0; k < 4; ++k) {
                const int rem = c4 + k, jj = rem & 7;
                const float nf = (i == jj) ? 1.f : sNiP[(x * 8 + i) * 7 + jj - (jj > i ? 1 : 0)];
                nvp[k] = nf;
                evp[k] = (i == jj) ? 1.f : 0.f;
            }
            const int bt = bt0 + x;
            if (bt < ROWSG) {
                *(float4*)(p.out + NN_OFF + (size_t)bt * 64 + c4) = nv;
                *(float4*)(p.out + EYE_OFF + (size_t)bt * 64 + c4) = ev;
            }
            *(float4*)(Nf + x * 64 + c4) = nv;
        }
    }
    __syncthreads();

    // ---- merged: q_ni (reads Nf + qvals direct) + P10s1 (reads ensB) — disjoint LDS ----
    if (t < RB * 32) {
        const float* Nf = attU;
        const int pr = t >> 2, q4 = t & 3;
        const int x = pr >> 3, i = pr & 7;
        const int j0 = q4 * 2;
        const int bt = bt0 + x;
        const size_t btc = (bt < ROWSG) ? bt : (ROWSG - 1);
        const float2 qv = *(const float2*)(p.qvals + btc * 8 + j0);
        const float2 nf2 = *(const float2*)(Nf + x * 64 + i * 8 + j0);
        float s = qv.x * nf2.x + qv.y * nf2.y;
        s += __shfl_xor(s, 1, 64);
        s += __shfl_xor(s, 2, 64);
        if (q4 == 0) qniL[x * 8 + i] = s;
    }
    // P10s1: t1 = relu(ens@w1a+b1a) -> Tb1(EbU); t2 = relu(ens@w2a+b2a) -> Tb2
    {
        const int n0 = w * 16;
#pragma unroll
        for (int m2 = 0; m2 < 2; ++m2) {
            const __bf16* wt = ws + (m2 == 0 ? OFF_W1A : OFF_W2A);
            const float* bias = m2 == 0 ? p.b1a : p.b2a;
            __bf16* dst = m2 == 0 ? EbU : Tb2;
            f32x4 acc = {0, 0, 0, 0};
#pragma unroll
            for (int ks = 0; ks < 4; ++ks) {
                const int kk = ks * 32 + quad * 8;
                const bf16x8 af = *(const bf16x8*)(ensB + l15 * 136 + kk);
                const bf16x8 bf = *(const bf16x8*)(wt + (size_t)(n0 + l15) * 128 + kk);
                acc = MFMA16(af, bf, acc);
            }
            const float bb = bias[n0 + l15];
#pragma unroll
            for (int r = 0; r < 4; ++r)
                dst[(quad * 4 + r) * HPAD + n0 + l15] = (__bf16)fmaxf(acc[r] + bb, 0.f);
        }
    }
    __syncthreads();

    // ---- P10s2: w1 (16 jobs), b1 (2), w2 (2), t3 (2) = 22 tile-jobs ----
    for (int it = 0; it < 6; ++it) {
        const int j = w + 4 * it;
        if (j >= 22) continue;
        int mode, n0, Kp, ksteps, aStride;
        const __bf16 *A, *WT; const float* bias;
        if (j < 16)      { mode = 0; n0 = j * 16;        A = EbU;  aStride = HPAD; WT = ws + OFF_W1B;   bias = p.b1b;  Kp = 64;  ksteps = 2; }
        else if (j < 18) { mode = 1; n0 = (j - 16) * 16; A = ensB; aStride = 136;  WT = ws + OFF_HB1W;  bias = p.hb1b; Kp = 128; ksteps = 4; }
        else if (j < 20) { mode = 2; n0 = (j - 18) * 16; A = Tb2;  aStride = HPAD; WT = ws + OFF_W2B;   bias = p.b2b;  Kp = 64;  ksteps = 2; }
        else             { mode = 3; n0 = (j - 20) * 16; A = ensB; aStride = 136;  WT = ws + OFF_HB2W1; bias = p.hb2b1;Kp = 128; ksteps = 4; }
        f32x4 acc = {0, 0, 0, 0};
        for (int ks = 0; ks < ksteps; ++ks) {
            const int kk = ks * 32 + quad * 8;
            const bf16x8 af = *(const bf16x8*)(A + l15 * aStride + kk);
            const bf16x8 bf = *(const bf16x8*)(WT + (size_t)(n0 + l15) * Kp + kk);
            acc = MFMA16(af, bf, acc);
        }
        const float bb = bias[n0 + l15];
#pragma unroll
        for (int r = 0; r < 4; ++r) {
            const int xr = quad * 4 + r;
            if (xr < RB) {
                const float val = acc[r] + bb;
                if (mode == 0)      W1bS[xr * 256 + n0 + l15] = (__bf16)fabsf(val);
                else if (mode == 1) B1f[xr * 32 + n0 + l15] = val;
                else if (mode == 2) W2f[xr * 32 + n0 + l15] = fabsf(val);
                else                T3f[xr * 32 + n0 + l15] = fmaxf(val, 0.f);
            }
        }
    }
    __syncthreads();

    // ---- P11: hidden = elu(q_ni@w1 + b1); y = hidden@w2 + t3@hw2 + hb2b2 ----
    if (t < RB * 16) {
        const int x = t >> 4, sub = t & 15;
        float pp = 0.f, pb = 0.f;
#pragma unroll
        for (int h2i = 0; h2i < 2; ++h2i) {
            const int e = sub + h2i * 16;
            float a = B1f[x * 32 + e];
#pragma unroll
            for (int i = 0; i < 8; ++i) a += qniL[x * 8 + i] * (float)W1bS[x * 256 + i * 32 + e];
            const float hid = a > 0.f ? a : (__expf(a) - 1.f);
            pp += hid * W2f[x * 32 + e];
            pb += T3f[x * 32 + e] * p.hw2[e];
        }
#pragma unroll
        for (int off = 1; off < 16; off <<= 1) {
            pp += __shfl_xor(pp, off, 64);
            pb += __shfl_xor(pb, off, 64);
        }
        const int bt = bt0 + x;
        if (sub == 0 && bt < ROWSG) p.out[bt] = pp + pb + p.hb2b2[0];
    }
}

extern "C" void kernel_launch(void* const* d_in, const int* in_sizes, int n_in,
                              void* d_out, int out_size, void* d_ws, size_t ws_size,
                              hipStream_t stream) {
    TP tp;
    tp.src[0]  = (const float*)d_in[3];   // enc_w1
    tp.src[1]  = (const float*)d_in[5];   // enc_w2
    tp.src[2]  = (const float*)d_in[7];   // wq
    tp.src[3]  = (const float*)d_in[9];   // wk
    tp.src[4]  = (const float*)d_in[11];  // wv
    tp.src[5]  = (const float*)d_in[13];  // wo
    tp.src[6]  = (const float*)d_in[17];  // ffn_w1
    tp.src[7]  = (const float*)d_in[19];  // ffn_w2
    tp.src[8]  = (const float*)d_in[27];  // w1a
    tp.src[9]  = (const float*)d_in[29];  // w1b
    tp.src[10] = (const float*)d_in[31];  // hb1w
    tp.src[11] = (const float*)d_in[33];  // w2a
    tp.src[12] = (const float*)d_in[35];  // w2b
    tp.src[13] = (const float*)d_in[37];  // hb2w1
    tp.src[14] = (const float*)d_in[23];  // fc2ni_w
    wtrans<<<(WS_TOTAL + 255) / 256, 256, 0, stream>>>(tp);

    MainP p;
    p.qvals = (const float*)d_in[0];
    p.states = (const float*)d_in[1];
    p.hid = (const float*)d_in[2];
    p.eb1 = (const float*)d_in[4];
    p.eb2 = (const float*)d_in[6];
    p.bq = (const float*)d_in[8];
    p.bk = (const float*)d_in[10];
    p.bv = (const float*)d_in[12];
    p.bo = (const float*)d_in[14];
    p.l1g = (const float*)d_in[15];
    p.l1b = (const float*)d_in[16];
    p.fb1 = (const float*)d_in[18];
    p.fb2 = (const float*)d_in[20];
    p.l2g = (const float*)d_in[21];
    p.l2b = (const float*)d_in[22];
    p.niw = (const float*)d_in[23];
    p.nib = (const float*)d_in[24];
    p.ng = (const float*)d_in[25];
    p.nb = (const float*)d_in[26];
    p.b1a = (const float*)d_in[28];
    p.b1b = (const float*)d_in[30];
    p.hb1b = (const float*)d_in[32];
    p.b2a = (const float*)d_in[34];
    p.b2b = (const float*)d_in[36];
    p.hb2b1 = (const float*)d_in[38];
    p.hw2 = (const float*)d_in[39];
    p.hb2b2 = (const float*)d_in[40];
    p.out = (float*)d_out;

    mixer_main<<<NBLK, 256, 0, stream>>>(p);
}